// Round 21
// baseline (1062.926 us; speedup 1.0000x reference)
//
#include <hip/hip_runtime.h>

typedef unsigned short u16;
typedef unsigned int   u32;
typedef __attribute__((ext_vector_type(8))) __bf16 bf16x8;
typedef __attribute__((ext_vector_type(4))) float  f32x4;
typedef __attribute__((ext_vector_type(4))) u16    u16x4;

#define DEV __device__ __forceinline__

// ---------- helpers ----------
DEV u16 f2b(float f) {               // fp32 -> bf16 bits, RNE
  union { float f; u32 u; } a; a.f = f;
  const u32 u = a.u;
  return (u16)((u + 0x7fffu + ((u >> 16) & 1u)) >> 16);
}

// tanh-form GELU as x*sigmoid(1.5957691*(x+0.044715 x^3)); exp2-folded.
DEV float gelu_fast(float x) {
  const float x2 = x * x;
  const float t  = __builtin_fmaf(0.1029430f, x2, 2.3022150f);  // *log2(e) folded
  const float e  = __builtin_exp2f(x * t);
  const float r  = __builtin_amdgcn_rcpf(1.0f + e);
  return __builtin_fmaf(-x, r, x);   // x - x/(1+e) = x*sigmoid(z)
}

DEV void gload16(const void* g, void* l) {
  __builtin_amdgcn_global_load_lds(
      (const __attribute__((address_space(1))) void*)g,
      (__attribute__((address_space(3))) void*)l, 16, 0, 0);
}

// ---------- weight conversion (fp32 -> bf16) ----------
__global__ __launch_bounds__(256)
void conv_weights(const float* __restrict__ qkvw, const float* __restrict__ projw,
                  const float* __restrict__ w1,   const float* __restrict__ w2,
                  u16* __restrict__ dq, u16* __restrict__ dp,
                  u16* __restrict__ d1, u16* __restrict__ d2) {
  const int t = blockIdx.x * 256 + threadIdx.x;
  if (t < 196608)      dq[t]          = f2b(qkvw[t]);
  else if (t < 262144) dp[t - 196608] = f2b(projw[t - 196608]);
  else if (t < 524288) d1[t - 262144] = f2b(w1[t - 262144]);
  else                 d2[t - 524288] = f2b(w2[t - 524288]);
}

// ---------- window gather + LN1, 4 adjacent windows per block ----------
__global__ __launch_bounds__(256)
void ln1_win(const float* __restrict__ x, const float* __restrict__ w1,
             const float* __restrict__ b1, u16* __restrict__ hout,
             float* __restrict__ xwout) {
  __shared__ float xt[64 * 257];
  __shared__ float smean[256], srstd[256];
  const int tid = threadIdx.x, lane = tid & 63, wv = tid >> 6;
  const int g = blockIdx.x;
  const int b = g / 196, rem = g % 196;
  const int wh = rem / 7, wg = rem % 7;
  const int base_r = b * 784 + wh * 28 + wg * 4;
  const int pr = tid >> 5, pc = tid & 31;
  int hp = wh * 8 + 4 + pr; if (hp >= 224) hp -= 224;
  int wp = wg * 32 + 4 + pc; if (wp >= 224) wp -= 224;
  const long roff = (long)b * 256 * 50176 + hp * 224 + wp;

  float s = 0.f, q = 0.f;
  for (int cc = 0; cc < 4; ++cc) {
#pragma unroll 8
    for (int i = 0; i < 64; ++i) {
      const int c = cc * 64 + i;
      const float v = x[(long)c * 50176 + roff];
      xt[i * 257 + tid] = v;
      s += v; q += v * v;
    }
    __syncthreads();
#pragma unroll 8
    for (int jj = 0; jj < 64; ++jj) {
      const int p = jj * 4 + wv;
      const int m = (base_r + ((p & 31) >> 3)) * 64 + (p >> 5) * 8 + (p & 7);
      xwout[(long)m * 256 + cc * 64 + lane] = xt[lane * 257 + p];
    }
    __syncthreads();
  }
  const float mean = s * (1.f / 256.f);
  smean[tid] = mean;
  srstd[tid] = rsqrtf(q * (1.f / 256.f) - mean * mean + 1e-5f);
  __syncthreads();

  float wr_[4], br_[4];
#pragma unroll
  for (int cc = 0; cc < 4; ++cc) { wr_[cc] = w1[cc * 64 + lane]; br_[cc] = b1[cc * 64 + lane]; }
#pragma unroll 2
  for (int jj = 0; jj < 64; ++jj) {
    const int p = jj * 4 + wv;
    const int m = (base_r + ((p & 31) >> 3)) * 64 + (p >> 5) * 8 + (p & 7);
    const float mu = smean[p], rs = srstd[p];
#pragma unroll
    for (int cc = 0; cc < 4; ++cc) {
      const float v = xwout[(long)m * 256 + cc * 64 + lane];
      hout[(long)m * 256 + cc * 64 + lane] = f2b((v - mu) * rs * wr_[cc] + br_[cc]);
    }
  }
}

// ---------- 128xNx(BK=32) bf16 GEMM (r11-measured), B given as [N][K] ----------
// In-block N-loop, 48 KB LDS dbuf, counted vmcnt(3), BK32 XOR swizzle.
// EPI 0: qkv (NCOL=3): cb<2 -> q|k u16x4 along d; cb==2 -> v^T
// EPI 1: y += acc + bias (float4 RMW) + FUSED LN2 -> bout bf16 (NCOL=1)
template<int EPI, int NCOL>
__global__ __launch_bounds__(512, 4)
void gemm_bt(const u16* __restrict__ A, const u16* __restrict__ Bw, const int K,
             float* __restrict__ fout, const float* __restrict__ bias,
             u16* __restrict__ bout,
             const float* __restrict__ lnw, const float* __restrict__ lnb) {
  __shared__ __align__(16) u16 smem[24576];   // 48 KB
  u16* sA0 = smem;             // 128x32
  u16* sB0 = smem + 4096;      // 256x32
  u16* sA1 = smem + 12288;
  u16* sB1 = smem + 16384;

  const int tid  = threadIdx.x;
  const int lane = tid & 63;
  const int wid  = tid >> 6;
  const int wrr  = wid >> 2;
  const int wcc  = wid & 3;

  const int nwg = gridDim.x;
  const int bid = blockIdx.x;
  const int wg  = (bid & 7) * (nwg >> 3) + (bid >> 3);   // XCD chunk swizzle
  const int row0 = wg * 128;

  const f32x4 vzero = {0.f, 0.f, 0.f, 0.f};

  const int l15  = lane & 15;
  const int l4   = lane >> 4;
  const int ksw2 = (l15 >> 1) & 3;
  const int lcol = (((tid & 3) ^ ((tid >> 3) & 3)) << 3);

  const u16* pA = A + (long)(row0 + (tid >> 2)) * K + lcol;
  const int wbase = wid * 512;

#define STAGE_TILE(KT, DA, DB)                  \
  {                                             \
    gload16(pA  + (KT), (DA) + wbase);          \
    gload16(pB  + (KT), (DB) + wbase);          \
    gload16(pB2 + (KT), (DB) + 4096 + wbase);   \
  }

#define COMPUTE_TILE(SA, SB, SWAP)                                                      \
  {                                                                                     \
    bf16x8 af[4], bfv[4];                                                               \
    _Pragma("unroll")                                                                   \
    for (int mi = 0; mi < 4; ++mi)                                                      \
      af[mi] = *(const bf16x8*)((SA) + (wrr * 64 + mi * 16 + l15) * 32 +                \
                                ((l4 ^ ksw2) << 3));                                    \
    _Pragma("unroll")                                                                   \
    for (int nj = 0; nj < 4; ++nj)                                                      \
      bfv[nj] = *(const bf16x8*)((SB) + (wcc * 64 + nj * 16 + l15) * 32 +               \
                                 ((l4 ^ ksw2) << 3));                                   \
    _Pragma("unroll")                                                                   \
    for (int mi = 0; mi < 4; ++mi)                                                      \
      _Pragma("unroll")                                                                 \
      for (int nj = 0; nj < 4; ++nj) {                                                  \
        if (SWAP)                                                                       \
          acc[mi][nj] = __builtin_amdgcn_mfma_f32_16x16x32_bf16(bfv[nj], af[mi],        \
                                                                acc[mi][nj], 0, 0, 0);  \
        else                                                                            \
          acc[mi][nj] = __builtin_amdgcn_mfma_f32_16x16x32_bf16(af[mi], bfv[nj],        \
                                                                acc[mi][nj], 0, 0, 0);  \
      }                                                                                 \
  }

#define KLOOP(SWAP)                                                  \
  {                                                                  \
    const int nt = K >> 5;                                           \
    STAGE_TILE(0, sA0, sB0);                                         \
    int cur = 0;                                                     \
    for (int t = 0; t < nt; ++t) {                                   \
      u16* cA = cur ? sA1 : sA0;                                     \
      u16* cB = cur ? sB1 : sB0;                                     \
      u16* nA = cur ? sA0 : sA1;                                     \
      u16* nB = cur ? sB0 : sB1;                                     \
      if (t + 1 < nt) {                                              \
        STAGE_TILE((t + 1) << 5, nA, nB);                            \
        asm volatile("s_waitcnt vmcnt(3)" ::: "memory");             \
      } else {                                                       \
        asm volatile("s_waitcnt vmcnt(0)" ::: "memory");             \
      }                                                              \
      __builtin_amdgcn_s_barrier();                                  \
      asm volatile("" ::: "memory");                                 \
      COMPUTE_TILE(cA, cB, SWAP);                                    \
      asm volatile("" ::: "memory");                                 \
      __builtin_amdgcn_s_barrier();                                  \
      cur ^= 1;                                                      \
    }                                                                \
  }

#pragma unroll
  for (int cb = 0; cb < NCOL; ++cb) {
    const int col0 = cb * 256;
    const u16* pB  = Bw + (long)(col0 + (tid >> 2)) * K + lcol;
    const u16* pB2 = pB + (long)128 * K;

    f32x4 acc[4][4];
#pragma unroll
    for (int i = 0; i < 4; ++i)
#pragma unroll
      for (int j = 0; j < 4; ++j) acc[i][j] = vzero;

    if (EPI == 0 && cb == 2) {
      // ---- v: unswapped orientation, v^T scatter (lane=n(d), reg=m(ii)) ----
      KLOOP(0);
#pragma unroll
      for (int mi = 0; mi < 4; ++mi) {
        const int mb = row0 + wrr * 64 + mi * 16 + (l4 << 2);
        const int rrg = mb >> 6, ii = mb & 63;
#pragma unroll
        for (int nj = 0; nj < 4; ++nj) {
          const int n = 512 + wcc * 64 + nj * 16 + l15;
          const int hh = (n >> 5) & 7, d = n & 31;
          u16x4 p;
#pragma unroll
          for (int reg = 0; reg < 4; ++reg) p[reg] = f2b(acc[mi][nj][reg]);
          *(u16x4*)(bout + 102760448L + (long)((rrg * 8 + hh) * 32 + d) * 64 + ii) = p;
        }
      }
      continue;
    }

    KLOOP(1);

    if (EPI == 0) {
      // q|k scatter, swapped orientation: lane=m, reg=n(d)
#pragma unroll
      for (int mi = 0; mi < 4; ++mi) {
        const int m = row0 + wrr * 64 + mi * 16 + l15;
        const int rr = m >> 6, ii = m & 63;
#pragma unroll
        for (int nj = 0; nj < 4; ++nj) {
          const int n = col0 + wcc * 64 + nj * 16 + (l4 << 2);
          const int s = n >> 8, hh = (n >> 5) & 7, d = n & 31;
          u16x4 p;
#pragma unroll
          for (int reg = 0; reg < 4; ++reg) p[reg] = f2b(acc[mi][nj][reg]);
          *(u16x4*)(bout + (long)s * 51380224L +
                    (long)((rr * 8 + hh) * 64 + ii) * 32 + d) = p;
        }
      }
    } else if (EPI == 1) {
      // y += acc + bias (float4 RMW), then fused LN2 -> bout (bf16 [m][256])
      f32x4 b4[4];
#pragma unroll
      for (int nj = 0; nj < 4; ++nj)
        b4[nj] = *(const f32x4*)(bias + wcc * 64 + nj * 16 + (l4 << 2));
      float sS[4], sQ[4];
#pragma unroll
      for (int mi = 0; mi < 4; ++mi) {
        const int m = row0 + wrr * 64 + mi * 16 + l15;
        float* yrow = fout + (long)m * 256;
        float s = 0.f, q = 0.f;
#pragma unroll
        for (int nj = 0; nj < 4; ++nj) {
          const int n = wcc * 64 + nj * 16 + (l4 << 2);
          f32x4 o = *(f32x4*)(yrow + n);
#pragma unroll
          for (int reg = 0; reg < 4; ++reg) {
            o[reg] += acc[mi][nj][reg] + b4[nj][reg];
            s += o[reg]; q += o[reg] * o[reg];
          }
          *(f32x4*)(yrow + n) = o;
          acc[mi][nj] = o;
        }
        s += __shfl_xor(s, 16); s += __shfl_xor(s, 32);
        q += __shfl_xor(q, 16); q += __shfl_xor(q, 32);
        sS[mi] = s; sQ[mi] = q;
      }
      float* ps = (float*)smem;          // [128 rows][4 wcc]
      float* pq = ps + 512;
      __syncthreads();
      if (lane < 16) {
#pragma unroll
        for (int mi = 0; mi < 4; ++mi) {
          const int idx = (wrr * 64 + mi * 16 + l15) * 4 + wcc;
          ps[idx] = sS[mi]; pq[idx] = sQ[mi];
        }
      }
      __syncthreads();
#pragma unroll
      for (int mi = 0; mi < 4; ++mi) {
        const int m = row0 + wrr * 64 + mi * 16 + l15;
        const int base = (wrr * 64 + mi * 16 + l15) * 4;
        const float S = ps[base] + ps[base + 1] + ps[base + 2] + ps[base + 3];
        const float Q = pq[base] + pq[base + 1] + pq[base + 2] + pq[base + 3];
        const float mean = S * (1.f / 256.f);
        const float rstd = rsqrtf(Q * (1.f / 256.f) - mean * mean + 1e-5f);
#pragma unroll
        for (int nj = 0; nj < 4; ++nj) {
          const int n = wcc * 64 + nj * 16 + (l4 << 2);
          const f32x4 w4 = *(const f32x4*)(lnw + n);
          const f32x4 c4 = *(const f32x4*)(lnb + n);
          u16x4 p;
#pragma unroll
          for (int reg = 0; reg < 4; ++reg)
            p[reg] = f2b((acc[mi][nj][reg] - mean) * rstd * w4[reg] + c4[reg]);
          *(u16x4*)(bout + (long)m * 256 + n) = p;
        }
      }
    }
  }
#undef STAGE_TILE
#undef COMPUTE_TILE
#undef KLOOP
}

// ---------- FUSED MLP v6: 16 waves (1024 thr), same 136 KB LDS / traffic ----------
// r18 structure (3-buffer rotation, 1 barrier/K-step) with wave tile 32x64:
// 4 waves/SIMD at the SAME 1 block/CU (2-block variants thrashed L2 — r15/r19).
// Staging: B (256 rows, 16 KB) = 1 load/thread (all 1024); A (128 rows, 8 KB)
// = 1 load/thread for waves 0-7. Per-wave counted vmcnt (2 vs 1) — each wave
// drains its OWN loads before every barrier, so post-barrier all data visible.
__global__ __launch_bounds__(1024, 4)
void mlp_fused(const u16* __restrict__ A, const u16* __restrict__ w1b,
               const u16* __restrict__ w2b, const float* __restrict__ y,
               const float* __restrict__ b1, const float* __restrict__ b2,
               float* __restrict__ oout) {
  __shared__ __align__(16) u16 smem[69632];   // 136 KB
  u16* bb0 = smem;                 // A @ +0 (8 KB), B @ +4096 u16 (16 KB)
  u16* bb1 = smem + 12288;
  u16* bb2 = smem + 24576;
  u16* H   = smem + 36864;         // 8 kt x 128 x 32 (64 KB)

  const int tid  = threadIdx.x;    // 0..1023
  const int lane = tid & 63;
  const int wid  = tid >> 6;       // 0..15
  const int wrr  = wid >> 2;       // 0..3 (32-row quarter)
  const int wcc  = wid & 3;        // 0..3 (64-col quarter)

  const int nwg = gridDim.x;
  const int bid = blockIdx.x;
  const int wg  = (bid & 7) * (nwg >> 3) + (bid >> 3);
  const int row0 = wg * 128;

  const f32x4 vzero = {0.f, 0.f, 0.f, 0.f};
  const int l15  = lane & 15;
  const int l4   = lane >> 4;
  const int ksw2 = (l15 >> 1) & 3;
  const int lcol = (((tid & 3) ^ ((tid >> 3) & 3)) << 3);

  const u16* pA = A + (long)(row0 + (tid >> 2)) * 256 + lcol;  // valid rows for tid<512
  const int wbase = wid * 512;     // per-wave linear 1 KB chunk

  f32x4 acc2[2][4];
#pragma unroll
  for (int i = 0; i < 2; ++i)
#pragma unroll
    for (int j = 0; j < 4; ++j) acc2[i][j] = vzero;

#define RD_A(BUF) \
  (*(const bf16x8*)((BUF) + (wrr * 32 + mi * 16 + l15) * 32 + ((l4 ^ ksw2) << 3)))
#define RD_B(BUF) \
  (*(const bf16x8*)((BUF) + 4096 + (wcc * 64 + nj * 16 + l15) * 32 + ((l4 ^ ksw2) << 3)))

  for (int cb = 0; cb < 4; ++cb) {
    // ---------------- GEMM1: hidden_cb = h2 @ w1[cb*256..+256)^T ----------
    const u16* pB = w1b + (long)(cb * 256 + (tid >> 2)) * 256 + lcol;  // rows 0..255

    f32x4 acc[2][4];
#pragma unroll
    for (int i = 0; i < 2; ++i)
#pragma unroll
      for (int j = 0; j < 4; ++j) acc[i][j] = vzero;

    {
      u16 *bc = bb0, *bn = bb1, *bo = bb2;
      // prologue: stage tile 0 into bc
      gload16(pB, bc + 4096 + wbase);
      if (wid < 8) gload16(pA, bc + wbase);
      for (int t = 0; t < 8; ++t) {
        if (t + 1 < 8) {
          const int kt = (t + 1) << 5;
          gload16(pB + kt, bn + 4096 + wbase);
          if (wid < 8) {
            gload16(pA + kt, bn + wbase);
            asm volatile("s_waitcnt vmcnt(2)" ::: "memory");
          } else {
            asm volatile("s_waitcnt vmcnt(1)" ::: "memory");
          }
        } else {
          asm volatile("s_waitcnt vmcnt(0)" ::: "memory");
        }
        __builtin_amdgcn_s_barrier();
        asm volatile("" ::: "memory");
        {
          bf16x8 af[2], bfv[4];
#pragma unroll
          for (int mi = 0; mi < 2; ++mi) af[mi] = RD_A(bc);
#pragma unroll
          for (int nj = 0; nj < 4; ++nj) bfv[nj] = RD_B(bc);
#pragma unroll
          for (int mi = 0; mi < 2; ++mi)
#pragma unroll
            for (int nj = 0; nj < 4; ++nj)
              acc[mi][nj] = __builtin_amdgcn_mfma_f32_16x16x32_bf16(
                  bfv[nj], af[mi], acc[mi][nj], 0, 0, 0);
        }
        asm volatile("" ::: "memory");
        u16* tmp = bc; bc = bn; bn = bo; bo = tmp;   // rotate (no 2nd barrier)
      }
    }

    // pre-issue GEMM2's first B-stage into bb0's B region (safe: bb0 last
    // read at GEMM1 compute(6); all waves passed barrier(7))
    const u16* qB = w2b + (long)(tid >> 2) * 1024 + cb * 256 + lcol;  // rows 0..255
    gload16(qB, bb0 + 4096 + wbase);

    // gelu + bf16 -> H (swizzled GEMM2-A layout). lane=m, reg quad = 4 k.
    {
      f32x4 b4[4];
#pragma unroll
      for (int nj = 0; nj < 4; ++nj)
        b4[nj] = *(const f32x4*)(b1 + cb * 256 + wcc * 64 + nj * 16 + (l4 << 2));
#pragma unroll
      for (int mi = 0; mi < 2; ++mi) {
        const int m = wrr * 32 + mi * 16 + l15;
#pragma unroll
        for (int nj = 0; nj < 4; ++nj) {
          u16x4 p;
#pragma unroll
          for (int reg = 0; reg < 4; ++reg)
            p[reg] = f2b(gelu_fast(acc[mi][nj][reg] + b4[nj][reg]));
          const int kt   = wcc * 2 + (nj >> 1);
          const int slot = ((nj & 1) << 1) + (l4 >> 1);
          *(u16x4*)(H + kt * 4096 + m * 32 +
                    ((slot ^ ((m >> 1) & 3)) << 3) + ((l4 & 1) << 2)) = p;
        }
      }
    }
    __syncthreads();   // H complete; all GEMM1 reads done

    // ---------------- GEMM2: acc2 += hidden_cb @ w2[:, cb*256..+256)^T ----
    {
      u16 *gc = bb0, *gn = bb1, *go = bb2;
      for (int kt = 0; kt < 8; ++kt) {
        if (kt + 1 < 8) {
          const int ko = (kt + 1) << 5;
          gload16(qB + ko, gn + 4096 + wbase);
          asm volatile("s_waitcnt vmcnt(1)" ::: "memory");
        } else {
          asm volatile("s_waitcnt vmcnt(0)" ::: "memory");
        }
        __builtin_amdgcn_s_barrier();
        asm volatile("" ::: "memory");
        {
          const u16* Hk = H + kt * 4096;
          bf16x8 af[2], bfv[4];
#pragma unroll
          for (int mi = 0; mi < 2; ++mi)
            af[mi] = *(const bf16x8*)(Hk + (wrr * 32 + mi * 16 + l15) * 32 +
                                      ((l4 ^ ksw2) << 3));
#pragma unroll
          for (int nj = 0; nj < 4; ++nj) bfv[nj] = RD_B(gc);
#pragma unroll
          for (int mi = 0; mi < 2; ++mi)
#pragma unroll
            for (int nj = 0; nj < 4; ++nj)
              acc2[mi][nj] = __builtin_amdgcn_mfma_f32_16x16x32_bf16(
                  bfv[nj], af[mi], acc2[mi][nj], 0, 0, 0);
        }
        asm volatile("" ::: "memory");
        u16* tmp = gc; gc = gn; gn = go; go = tmp;   // rotate (no 2nd barrier)
      }
    }
    __syncthreads();   // cb boundary: staging buffers + H free for reuse
  }
#undef RD_A
#undef RD_B

  // ---------------- epilogue: o = y + acc2 + b2; fused un-window ----------
  {
    f32x4 b4[4];
#pragma unroll
    for (int nj = 0; nj < 4; ++nj)
      b4[nj] = *(const f32x4*)(b2 + wcc * 64 + nj * 16 + (l4 << 2));
#pragma unroll
    for (int mi = 0; mi < 2; ++mi) {
      const int m = row0 + wrr * 32 + mi * 16 + l15;
      const float* yrow = y + (long)m * 256;
#pragma unroll
      for (int nj = 0; nj < 4; ++nj) {
        const int n = wcc * 64 + nj * 16 + (l4 << 2);
        const f32x4 yv = *(const f32x4*)(yrow + n);
#pragma unroll
        for (int reg = 0; reg < 4; ++reg)
          acc2[mi][nj][reg] += yv[reg] + b4[nj][reg];
      }
    }
    // 128 rows = 2 windows (same wh, ww = wwb, wwb+1) = 8 img rows x 16 cols
    const int wr0 = row0 >> 6;
    const int b = wr0 / 784, rem = wr0 % 784;
    const int wh = rem / 28, wwb = rem % 28;       // wwb even
    float* tp = (float*)smem;                      // [64 c][128 px] f32, swizzled
    const int pidx = tid & 127, cgrp = tid >> 7;   // 8 cgrps x 128 px
    const int pr = pidx >> 4, pc = pidx & 15;
    int hp = wh * 8 + 4 + pr;  if (hp >= 224) hp -= 224;
    int wp = wwb * 8 + 4 + pc; if (wp >= 224) wp -= 224;
    float* ob = oout + (long)b * 256 * 50176 + hp * 224 + wp;
#pragma unroll
    for (int cc = 0; cc < 4; ++cc) {
      __syncthreads();
      if (wcc == cc) {
#pragma unroll
        for (int mi = 0; mi < 2; ++mi) {
          const int ml = wrr * 32 + mi * 16 + l15;
          const int px = ((ml & 63) >> 3) * 16 + (ml >> 6) * 8 + (ml & 7);
#pragma unroll
          for (int nj = 0; nj < 4; ++nj)
#pragma unroll
            for (int reg = 0; reg < 4; ++reg)
              tp[(nj * 16 + (l4 << 2) + reg) * 128 + (px ^ (l4 << 2))] =
                  acc2[mi][nj][reg];
        }
      }
      __syncthreads();
#pragma unroll 4
      for (int j = 0; j < 8; ++j) {
        const int cl = cgrp * 8 + j;
        ob[(long)(cc * 64 + cl) * 50176] =
            tp[cl * 128 + (pidx ^ (((cl >> 2) & 3) << 2))];
      }
    }
  }
}

// ---------- per-window attention: 1 wave = 1 head ----------
__global__ __launch_bounds__(256)
void attn_win(const u16* __restrict__ qkv, const float* __restrict__ rpb,
              u16* __restrict__ aout) {
  __shared__ u16 Pl[4][4096];
  __shared__ float srpb[1800];
  const int tid = threadIdx.x, lane = tid & 63, wv = tid >> 6;
  const int bid = blockIdx.x;
  const int r = bid >> 1;
  const int h = (bid & 1) * 4 + wv;
  for (int i = tid; i < 1800; i += 256) srpb[i] = rpb[i];
  __syncthreads();

  // reference quirk: jnp.repeat(mask, B, axis=0) -> window r uses mask[r/4]
  const int midx = r >> 2;
  const int wh = midx / 28, ww = midx % 28;
  const int l15 = lane & 15, l4 = lane >> 4;

  u16* Pw = &Pl[wv][0];
  const long hb = (long)(r * 8 + h) * 2048;
  const u16* qh = qkv + hb;
  const u16* kh = qkv + 51380224 + hb;
  const u16* vh = qkv + 102760448 + hb;

  int rj[4], cj[4], labj[4];
#pragma unroll
  for (int nj = 0; nj < 4; ++nj) {
    const int j = nj * 16 + l15;
    rj[nj] = j >> 3; cj[nj] = j & 7;
    const int hp = wh * 8 + rj[nj], wp = ww * 8 + cj[nj];
    const int lh = (hp < 216) ? 0 : ((hp < 220) ? 1 : 2);
    const int lw = (wp < 216) ? 0 : ((wp < 220) ? 1 : 2);
    labj[nj] = lh * 3 + lw;
  }

  const f32x4 vzero = {0.f, 0.f, 0.f, 0.f};

  bf16x8 qf[4], kf[4];
#pragma unroll
  for (int mi = 0; mi < 4; ++mi)
    qf[mi] = *(const bf16x8*)(qh + (mi * 16 + l15) * 32 + l4 * 8);
#pragma unroll
  for (int nj = 0; nj < 4; ++nj)
    kf[nj] = *(const bf16x8*)(kh + (nj * 16 + l15) * 32 + l4 * 8);

  f32x4 S[4][4];
#pragma unroll
  for (int mi = 0; mi < 4; ++mi)
#pragma unroll
    for (int nj = 0; nj < 4; ++nj)
      S[mi][nj] = __builtin_amdgcn_mfma_f32_16x16x32_bf16(qf[mi], kf[nj], vzero, 0, 0, 0);

  // softmax (row-parallel over 16-lane groups) + normalized bf16 P -> LDS
#pragma unroll
  for (int mi = 0; mi < 4; ++mi)
#pragma unroll
    for (int reg = 0; reg < 4; ++reg) {
      const int i = mi * 16 + (l4 << 2) + reg;
      const int ri = i >> 3, ci = i & 7;
      const int hp = wh * 8 + ri, wp = ww * 8 + ci;
      const int lh = (hp < 216) ? 0 : ((hp < 220) ? 1 : 2);
      const int lw = (wp < 216) ? 0 : ((wp < 220) ? 1 : 2);
      const int li = lh * 3 + lw;
      float v[4];
#pragma unroll
      for (int nj = 0; nj < 4; ++nj) {
        const int idx = (ri - rj[nj] + 7) * 15 + (ci - cj[nj] + 7);
        v[nj] = S[mi][nj][reg] * 0.17677669529663687f + srpb[idx * 8 + h]
              + ((li != labj[nj]) ? -100.0f : 0.0f);
      }
      float mx = fmaxf(fmaxf(v[0], v[1]), fmaxf(v[2], v[3]));
      mx = fmaxf(mx, __shfl_xor(mx, 1));
      mx = fmaxf(mx, __shfl_xor(mx, 2));
      mx = fmaxf(mx, __shfl_xor(mx, 4));
      mx = fmaxf(mx, __shfl_xor(mx, 8));
      float sum = 0.f;
#pragma unroll
      for (int nj = 0; nj < 4; ++nj) { v[nj] = __expf(v[nj] - mx); sum += v[nj]; }
      sum += __shfl_xor(sum, 1);
      sum += __shfl_xor(sum, 2);
      sum += __shfl_xor(sum, 4);
      sum += __shfl_xor(sum, 8);
      const float rinv = __builtin_amdgcn_rcpf(sum);
      const int sw = (i & 7) << 3;
#pragma unroll
      for (int nj = 0; nj < 4; ++nj)
        Pw[i * 64 + ((nj * 16 + l15) ^ sw)] = f2b(v[nj] * rinv);
    }

  // PV: O^T = mfma(V^T, P) — per-wave LDS, no barrier needed
  f32x4 OT[2][4];
#pragma unroll
  for (int td = 0; td < 2; ++td)
#pragma unroll
    for (int ti = 0; ti < 4; ++ti) OT[td][ti] = vzero;

  const int rsw = (l15 & 7) << 3;
#pragma unroll
  for (int kk = 0; kk < 2; ++kk) {
    bf16x8 pf[4], vf[2];
#pragma unroll
    for (int ti = 0; ti < 4; ++ti)
      pf[ti] = *(const bf16x8*)(Pw + (ti * 16 + l15) * 64 + ((kk * 32 + l4 * 8) ^ rsw));
#pragma unroll
    for (int td = 0; td < 2; ++td)
      vf[td] = *(const bf16x8*)(vh + (td * 16 + l15) * 64 + kk * 32 + l4 * 8);
#pragma unroll
    for (int td = 0; td < 2; ++td)
#pragma unroll
      for (int ti = 0; ti < 4; ++ti)
        OT[td][ti] = __builtin_amdgcn_mfma_f32_16x16x32_bf16(vf[td], pf[ti], OT[td][ti], 0, 0, 0);
  }

  // write: lane holds O[i=ti*16+l15][d=td*16+4*l4+reg] -> u16x4 along d
#pragma unroll
  for (int td = 0; td < 2; ++td)
#pragma unroll
    for (int ti = 0; ti < 4; ++ti) {
      const int i = ti * 16 + l15;
      const int d0 = td * 16 + (l4 << 2);
      u16x4 p;
#pragma unroll
      for (int reg = 0; reg < 4; ++reg) p[reg] = f2b(OT[td][ti][reg]);
      *(u16x4*)(aout + (long)(r * 64 + i) * 256 + h * 32 + d0) = p;
    }
}

// ---------- launch ----------
extern "C" void kernel_launch(void* const* d_in, const int* in_sizes, int n_in,
                              void* d_out, int out_size, void* d_ws, size_t ws_size,
                              hipStream_t stream) {
  (void)in_sizes; (void)n_in; (void)out_size; (void)ws_size;
  const float* x     = (const float*)d_in[0];
  const float* qkvw  = (const float*)d_in[1];
  const float* projw = (const float*)d_in[2];
  const float* projb = (const float*)d_in[3];
  const float* rpb   = (const float*)d_in[4];
  const float* n1w   = (const float*)d_in[5];
  const float* n1b   = (const float*)d_in[6];
  const float* n2w   = (const float*)d_in[7];
  const float* n2b   = (const float*)d_in[8];
  const float* w1    = (const float*)d_in[9];
  const float* b1    = (const float*)d_in[10];
  const float* w2    = (const float*)d_in[11];
  const float* b2    = (const float*)d_in[12];

  char* ws = (char*)d_ws;
  u16*   hbuf   = (u16*)(ws);                  // 102,760,448 B : h, later h2
  u16*   qkvb   = (u16*)(ws + 102760448);      // 308,281,344 B : q|k|v
  u16*   abuf   = (u16*)(ws + 411041792);      // 102,760,448 B : attn out
  float* ybuf   = (float*)(ws + 513802240);    // 205,520,896 B : fp32 residual stream
  u16*   qkvwb  = (u16*)(ws + 719323136);
  u16*   projwb = (u16*)(ws + 719716352);
  u16*   w1b    = (u16*)(ws + 719847424);
  u16*   w2b    = (u16*)(ws + 720371712);      // end: 720,896,000 B

  conv_weights<<<3072, 256, 0, stream>>>(qkvw, projw, w1, w2, qkvwb, projwb, w1b, w2b);
  ln1_win<<<784, 256, 0, stream>>>(x, n1w, n1b, hbuf, ybuf);
  gemm_bt<0, 3><<<1568, 512, 0, stream>>>(hbuf, qkvwb, 256, nullptr, nullptr, qkvb, nullptr, nullptr);
  attn_win<<<6272, 256, 0, stream>>>(qkvb, rpb, abuf);
  gemm_bt<1, 1><<<1568, 512, 0, stream>>>(abuf, projwb, 256, ybuf, projb, hbuf, n2w, n2b);
  mlp_fused<<<1568, 1024, 0, stream>>>(hbuf, w1b, w2b, ybuf, b1, b2, (float*)d_out);
}

// Round 22
// 1031.266 us; speedup vs baseline: 1.0307x; 1.0307x over previous
//
#include <hip/hip_runtime.h>

typedef unsigned short u16;
typedef unsigned int   u32;
typedef __attribute__((ext_vector_type(8))) __bf16 bf16x8;
typedef __attribute__((ext_vector_type(4))) float  f32x4;
typedef __attribute__((ext_vector_type(4))) u16    u16x4;

#define DEV __device__ __forceinline__

// ---------- helpers ----------
DEV u16 f2b(float f) {               // fp32 -> bf16 bits, RNE
  union { float f; u32 u; } a; a.f = f;
  const u32 u = a.u;
  return (u16)((u + 0x7fffu + ((u >> 16) & 1u)) >> 16);
}

// tanh-form GELU as x*sigmoid(1.5957691*(x+0.044715 x^3)); exp2-folded.
DEV float gelu_fast(float x) {
  const float x2 = x * x;
  const float t  = __builtin_fmaf(0.1029430f, x2, 2.3022150f);  // *log2(e) folded
  const float e  = __builtin_exp2f(x * t);
  const float r  = __builtin_amdgcn_rcpf(1.0f + e);
  return __builtin_fmaf(-x, r, x);   // x - x/(1+e) = x*sigmoid(z)
}

DEV void gload16(const void* g, void* l) {
  __builtin_amdgcn_global_load_lds(
      (const __attribute__((address_space(1))) void*)g,
      (__attribute__((address_space(3))) void*)l, 16, 0, 0);
}

// ---------- weight conversion (fp32 -> bf16) ----------
__global__ __launch_bounds__(256)
void conv_weights(const float* __restrict__ qkvw, const float* __restrict__ projw,
                  const float* __restrict__ w1,   const float* __restrict__ w2,
                  u16* __restrict__ dq, u16* __restrict__ dp,
                  u16* __restrict__ d1, u16* __restrict__ d2) {
  const int t = blockIdx.x * 256 + threadIdx.x;
  if (t < 196608)      dq[t]          = f2b(qkvw[t]);
  else if (t < 262144) dp[t - 196608] = f2b(projw[t - 196608]);
  else if (t < 524288) d1[t - 262144] = f2b(w1[t - 262144]);
  else                 d2[t - 524288] = f2b(w2[t - 524288]);
}

// ---------- window gather + LN1, 4 adjacent windows per block ----------
__global__ __launch_bounds__(256)
void ln1_win(const float* __restrict__ x, const float* __restrict__ w1,
             const float* __restrict__ b1, u16* __restrict__ hout,
             float* __restrict__ xwout) {
  __shared__ float xt[64 * 257];
  __shared__ float smean[256], srstd[256];
  const int tid = threadIdx.x, lane = tid & 63, wv = tid >> 6;
  const int g = blockIdx.x;
  const int b = g / 196, rem = g % 196;
  const int wh = rem / 7, wg = rem % 7;
  const int base_r = b * 784 + wh * 28 + wg * 4;
  const int pr = tid >> 5, pc = tid & 31;
  int hp = wh * 8 + 4 + pr; if (hp >= 224) hp -= 224;
  int wp = wg * 32 + 4 + pc; if (wp >= 224) wp -= 224;
  const long roff = (long)b * 256 * 50176 + hp * 224 + wp;

  float s = 0.f, q = 0.f;
  for (int cc = 0; cc < 4; ++cc) {
#pragma unroll 8
    for (int i = 0; i < 64; ++i) {
      const int c = cc * 64 + i;
      const float v = x[(long)c * 50176 + roff];
      xt[i * 257 + tid] = v;
      s += v; q += v * v;
    }
    __syncthreads();
#pragma unroll 8
    for (int jj = 0; jj < 64; ++jj) {
      const int p = jj * 4 + wv;
      const int m = (base_r + ((p & 31) >> 3)) * 64 + (p >> 5) * 8 + (p & 7);
      xwout[(long)m * 256 + cc * 64 + lane] = xt[lane * 257 + p];
    }
    __syncthreads();
  }
  const float mean = s * (1.f / 256.f);
  smean[tid] = mean;
  srstd[tid] = rsqrtf(q * (1.f / 256.f) - mean * mean + 1e-5f);
  __syncthreads();

  float wr_[4], br_[4];
#pragma unroll
  for (int cc = 0; cc < 4; ++cc) { wr_[cc] = w1[cc * 64 + lane]; br_[cc] = b1[cc * 64 + lane]; }
#pragma unroll 2
  for (int jj = 0; jj < 64; ++jj) {
    const int p = jj * 4 + wv;
    const int m = (base_r + ((p & 31) >> 3)) * 64 + (p >> 5) * 8 + (p & 7);
    const float mu = smean[p], rs = srstd[p];
#pragma unroll
    for (int cc = 0; cc < 4; ++cc) {
      const float v = xwout[(long)m * 256 + cc * 64 + lane];
      hout[(long)m * 256 + cc * 64 + lane] = f2b((v - mu) * rs * wr_[cc] + br_[cc]);
    }
  }
}

// ---------- 128xNx(BK=32) bf16 GEMM (r11-measured), B given as [N][K] ----------
// In-block N-loop, 48 KB LDS dbuf, counted vmcnt(3), BK32 XOR swizzle.
// EPI 0: qkv (NCOL=3): cb<2 -> q|k u16x4 along d; cb==2 -> v^T
// EPI 1: y += acc + bias (float4 RMW) + FUSED LN2 -> bout bf16 (NCOL=1)
template<int EPI, int NCOL>
__global__ __launch_bounds__(512, 4)
void gemm_bt(const u16* __restrict__ A, const u16* __restrict__ Bw, const int K,
             float* __restrict__ fout, const float* __restrict__ bias,
             u16* __restrict__ bout,
             const float* __restrict__ lnw, const float* __restrict__ lnb) {
  __shared__ __align__(16) u16 smem[24576];   // 48 KB
  u16* sA0 = smem;             // 128x32
  u16* sB0 = smem + 4096;      // 256x32
  u16* sA1 = smem + 12288;
  u16* sB1 = smem + 16384;

  const int tid  = threadIdx.x;
  const int lane = tid & 63;
  const int wid  = tid >> 6;
  const int wrr  = wid >> 2;
  const int wcc  = wid & 3;

  const int nwg = gridDim.x;
  const int bid = blockIdx.x;
  const int wg  = (bid & 7) * (nwg >> 3) + (bid >> 3);   // XCD chunk swizzle
  const int row0 = wg * 128;

  const f32x4 vzero = {0.f, 0.f, 0.f, 0.f};

  const int l15  = lane & 15;
  const int l4   = lane >> 4;
  const int ksw2 = (l15 >> 1) & 3;
  const int lcol = (((tid & 3) ^ ((tid >> 3) & 3)) << 3);

  const u16* pA = A + (long)(row0 + (tid >> 2)) * K + lcol;
  const int wbase = wid * 512;

#define STAGE_TILE(KT, DA, DB)                  \
  {                                             \
    gload16(pA  + (KT), (DA) + wbase);          \
    gload16(pB  + (KT), (DB) + wbase);          \
    gload16(pB2 + (KT), (DB) + 4096 + wbase);   \
  }

#define COMPUTE_TILE(SA, SB, SWAP)                                                      \
  {                                                                                     \
    bf16x8 af[4], bfv[4];                                                               \
    _Pragma("unroll")                                                                   \
    for (int mi = 0; mi < 4; ++mi)                                                      \
      af[mi] = *(const bf16x8*)((SA) + (wrr * 64 + mi * 16 + l15) * 32 +                \
                                ((l4 ^ ksw2) << 3));                                    \
    _Pragma("unroll")                                                                   \
    for (int nj = 0; nj < 4; ++nj)                                                      \
      bfv[nj] = *(const bf16x8*)((SB) + (wcc * 64 + nj * 16 + l15) * 32 +               \
                                 ((l4 ^ ksw2) << 3));                                   \
    _Pragma("unroll")                                                                   \
    for (int mi = 0; mi < 4; ++mi)                                                      \
      _Pragma("unroll")                                                                 \
      for (int nj = 0; nj < 4; ++nj) {                                                  \
        if (SWAP)                                                                       \
          acc[mi][nj] = __builtin_amdgcn_mfma_f32_16x16x32_bf16(bfv[nj], af[mi],        \
                                                                acc[mi][nj], 0, 0, 0);  \
        else                                                                            \
          acc[mi][nj] = __builtin_amdgcn_mfma_f32_16x16x32_bf16(af[mi], bfv[nj],        \
                                                                acc[mi][nj], 0, 0, 0);  \
      }                                                                                 \
  }

#define KLOOP(SWAP)                                                  \
  {                                                                  \
    const int nt = K >> 5;                                           \
    STAGE_TILE(0, sA0, sB0);                                         \
    int cur = 0;                                                     \
    for (int t = 0; t < nt; ++t) {                                   \
      u16* cA = cur ? sA1 : sA0;                                     \
      u16* cB = cur ? sB1 : sB0;                                     \
      u16* nA = cur ? sA0 : sA1;                                     \
      u16* nB = cur ? sB0 : sB1;                                     \
      if (t + 1 < nt) {                                              \
        STAGE_TILE((t + 1) << 5, nA, nB);                            \
        asm volatile("s_waitcnt vmcnt(3)" ::: "memory");             \
      } else {                                                       \
        asm volatile("s_waitcnt vmcnt(0)" ::: "memory");             \
      }                                                              \
      __builtin_amdgcn_s_barrier();                                  \
      asm volatile("" ::: "memory");                                 \
      COMPUTE_TILE(cA, cB, SWAP);                                    \
      asm volatile("" ::: "memory");                                 \
      __builtin_amdgcn_s_barrier();                                  \
      cur ^= 1;                                                      \
    }                                                                \
  }

#pragma unroll
  for (int cb = 0; cb < NCOL; ++cb) {
    const int col0 = cb * 256;
    const u16* pB  = Bw + (long)(col0 + (tid >> 2)) * K + lcol;
    const u16* pB2 = pB + (long)128 * K;

    f32x4 acc[4][4];
#pragma unroll
    for (int i = 0; i < 4; ++i)
#pragma unroll
      for (int j = 0; j < 4; ++j) acc[i][j] = vzero;

    if (EPI == 0 && cb == 2) {
      // ---- v: unswapped orientation, v^T scatter (lane=n(d), reg=m(ii)) ----
      KLOOP(0);
#pragma unroll
      for (int mi = 0; mi < 4; ++mi) {
        const int mb = row0 + wrr * 64 + mi * 16 + (l4 << 2);
        const int rrg = mb >> 6, ii = mb & 63;
#pragma unroll
        for (int nj = 0; nj < 4; ++nj) {
          const int n = 512 + wcc * 64 + nj * 16 + l15;
          const int hh = (n >> 5) & 7, d = n & 31;
          u16x4 p;
#pragma unroll
          for (int reg = 0; reg < 4; ++reg) p[reg] = f2b(acc[mi][nj][reg]);
          *(u16x4*)(bout + 102760448L + (long)((rrg * 8 + hh) * 32 + d) * 64 + ii) = p;
        }
      }
      continue;
    }

    KLOOP(1);

    if (EPI == 0) {
      // q|k scatter, swapped orientation: lane=m, reg=n(d)
#pragma unroll
      for (int mi = 0; mi < 4; ++mi) {
        const int m = row0 + wrr * 64 + mi * 16 + l15;
        const int rr = m >> 6, ii = m & 63;
#pragma unroll
        for (int nj = 0; nj < 4; ++nj) {
          const int n = col0 + wcc * 64 + nj * 16 + (l4 << 2);
          const int s = n >> 8, hh = (n >> 5) & 7, d = n & 31;
          u16x4 p;
#pragma unroll
          for (int reg = 0; reg < 4; ++reg) p[reg] = f2b(acc[mi][nj][reg]);
          *(u16x4*)(bout + (long)s * 51380224L +
                    (long)((rr * 8 + hh) * 64 + ii) * 32 + d) = p;
        }
      }
    } else if (EPI == 1) {
      // y += acc + bias (float4 RMW), then fused LN2 -> bout (bf16 [m][256])
      f32x4 b4[4];
#pragma unroll
      for (int nj = 0; nj < 4; ++nj)
        b4[nj] = *(const f32x4*)(bias + wcc * 64 + nj * 16 + (l4 << 2));
      float sS[4], sQ[4];
#pragma unroll
      for (int mi = 0; mi < 4; ++mi) {
        const int m = row0 + wrr * 64 + mi * 16 + l15;
        float* yrow = fout + (long)m * 256;
        float s = 0.f, q = 0.f;
#pragma unroll
        for (int nj = 0; nj < 4; ++nj) {
          const int n = wcc * 64 + nj * 16 + (l4 << 2);
          f32x4 o = *(f32x4*)(yrow + n);
#pragma unroll
          for (int reg = 0; reg < 4; ++reg) {
            o[reg] += acc[mi][nj][reg] + b4[nj][reg];
            s += o[reg]; q += o[reg] * o[reg];
          }
          *(f32x4*)(yrow + n) = o;
          acc[mi][nj] = o;
        }
        s += __shfl_xor(s, 16); s += __shfl_xor(s, 32);
        q += __shfl_xor(q, 16); q += __shfl_xor(q, 32);
        sS[mi] = s; sQ[mi] = q;
      }
      float* ps = (float*)smem;          // [128 rows][4 wcc]
      float* pq = ps + 512;
      __syncthreads();
      if (lane < 16) {
#pragma unroll
        for (int mi = 0; mi < 4; ++mi) {
          const int idx = (wrr * 64 + mi * 16 + l15) * 4 + wcc;
          ps[idx] = sS[mi]; pq[idx] = sQ[mi];
        }
      }
      __syncthreads();
#pragma unroll
      for (int mi = 0; mi < 4; ++mi) {
        const int m = row0 + wrr * 64 + mi * 16 + l15;
        const int base = (wrr * 64 + mi * 16 + l15) * 4;
        const float S = ps[base] + ps[base + 1] + ps[base + 2] + ps[base + 3];
        const float Q = pq[base] + pq[base + 1] + pq[base + 2] + pq[base + 3];
        const float mean = S * (1.f / 256.f);
        const float rstd = rsqrtf(Q * (1.f / 256.f) - mean * mean + 1e-5f);
#pragma unroll
        for (int nj = 0; nj < 4; ++nj) {
          const int n = wcc * 64 + nj * 16 + (l4 << 2);
          const f32x4 w4 = *(const f32x4*)(lnw + n);
          const f32x4 c4 = *(const f32x4*)(lnb + n);
          u16x4 p;
#pragma unroll
          for (int reg = 0; reg < 4; ++reg)
            p[reg] = f2b((acc[mi][nj][reg] - mean) * rstd * w4[reg] + c4[reg]);
          *(u16x4*)(bout + (long)m * 256 + n) = p;
        }
      }
    }
  }
#undef STAGE_TILE
#undef COMPUTE_TILE
#undef KLOOP
}

// ---------- FUSED MLP v4 (r16 + 3-buffer rotation, 1 barrier/K-step) ----------
// LDS: 3 x (A 8K + B 16K) staging = 72 KB + H 64 KB = 136 KB.
// Per K-step: STAGE(t+1 -> buf[(t+1)%3]); counted vmcnt; barrier; COMPUTE(buf[t%3]).
// Trailing barrier eliminated: STAGE(t+1) overwrites the buffer last read at
// compute(t-2), already guaranteed done by barrier(t-1). Barriers/cb: 34 -> 18.
// NOTE: 1 block/CU with 8 waves is deliberate — every occupancy variant
// regressed through a memory-system mechanism: 2 blocks/CU (r15: 845 MB,
// r19: 1.2 GB FETCH, L2 thrash), 16 waves/block (r21: WRITE 218->350 MB,
// worse write-combining). This config: FETCH 179 MB, WRITE 218 MB, 430 us.
__global__ __launch_bounds__(512, 2)
void mlp_fused(const u16* __restrict__ A, const u16* __restrict__ w1b,
               const u16* __restrict__ w2b, const float* __restrict__ y,
               const float* __restrict__ b1, const float* __restrict__ b2,
               float* __restrict__ oout) {
  __shared__ __align__(16) u16 smem[69632];   // 136 KB
  u16* bb0 = smem;                 // A @ +0 (8 KB), B @ +4096 (16 KB)
  u16* bb1 = smem + 12288;
  u16* bb2 = smem + 24576;
  u16* H   = smem + 36864;         // 8 kt x 128 x 32 (64 KB)

  const int tid  = threadIdx.x;
  const int lane = tid & 63;
  const int wid  = tid >> 6;
  const int wrr  = wid >> 2;
  const int wcc  = wid & 3;

  const int nwg = gridDim.x;
  const int bid = blockIdx.x;
  const int wg  = (bid & 7) * (nwg >> 3) + (bid >> 3);
  const int row0 = wg * 128;

  const f32x4 vzero = {0.f, 0.f, 0.f, 0.f};
  const int l15  = lane & 15;
  const int l4   = lane >> 4;
  const int ksw2 = (l15 >> 1) & 3;
  const int lcol = (((tid & 3) ^ ((tid >> 3) & 3)) << 3);

  const u16* pA = A + (long)(row0 + (tid >> 2)) * 256 + lcol;
  const int wbase = wid * 512;

  f32x4 acc2[4][4];
#pragma unroll
  for (int i = 0; i < 4; ++i)
#pragma unroll
    for (int j = 0; j < 4; ++j) acc2[i][j] = vzero;

#define RD_A(BUF) \
  (*(const bf16x8*)((BUF) + (wrr * 64 + mi * 16 + l15) * 32 + ((l4 ^ ksw2) << 3)))
#define RD_B(BUF) \
  (*(const bf16x8*)((BUF) + 4096 + (wcc * 64 + nj * 16 + l15) * 32 + ((l4 ^ ksw2) << 3)))

  for (int cb = 0; cb < 4; ++cb) {
    // ---------------- GEMM1: hidden_cb = h2 @ w1[cb*256..+256)^T ----------
    const u16* pB  = w1b + (long)(cb * 256 + (tid >> 2)) * 256 + lcol;
    const u16* pB2 = pB + 128 * 256;

    f32x4 acc[4][4];
#pragma unroll
    for (int i = 0; i < 4; ++i)
#pragma unroll
      for (int j = 0; j < 4; ++j) acc[i][j] = vzero;

    {
      u16 *bc = bb0, *bn = bb1, *bo = bb2;
      // prologue: stage tile 0 into bc
      gload16(pA, bc + wbase);
      gload16(pB, bc + 4096 + wbase);
      gload16(pB2, bc + 8192 + wbase);
      for (int t = 0; t < 8; ++t) {
        if (t + 1 < 8) {
          const int kt = (t + 1) << 5;
          gload16(pA + kt, bn + wbase);
          gload16(pB + kt, bn + 4096 + wbase);
          gload16(pB2 + kt, bn + 8192 + wbase);
          asm volatile("s_waitcnt vmcnt(3)" ::: "memory");
        } else {
          asm volatile("s_waitcnt vmcnt(0)" ::: "memory");
        }
        __builtin_amdgcn_s_barrier();
        asm volatile("" ::: "memory");
        {
          bf16x8 af[4], bfv[4];
#pragma unroll
          for (int mi = 0; mi < 4; ++mi) af[mi] = RD_A(bc);
#pragma unroll
          for (int nj = 0; nj < 4; ++nj) bfv[nj] = RD_B(bc);
#pragma unroll
          for (int mi = 0; mi < 4; ++mi)
#pragma unroll
            for (int nj = 0; nj < 4; ++nj)
              acc[mi][nj] = __builtin_amdgcn_mfma_f32_16x16x32_bf16(
                  bfv[nj], af[mi], acc[mi][nj], 0, 0, 0);
        }
        asm volatile("" ::: "memory");
        u16* tmp = bc; bc = bn; bn = bo; bo = tmp;   // rotate (no 2nd barrier)
      }
    }

    // pre-issue GEMM2's first B-stage into bb0's B region (safe: bb0 last
    // read at GEMM1 compute(6); all waves passed barrier(7))
    const u16* qB  = w2b + (long)(tid >> 2) * 1024 + cb * 256 + lcol;
    const u16* qB2 = qB + 128 * 1024;
    gload16(qB, bb0 + 4096 + wbase);
    gload16(qB2, bb0 + 8192 + wbase);

    // gelu + bf16 -> H (swizzled GEMM2-A layout). lane=m, reg quad = 4 k.
    {
      f32x4 b4[4];
#pragma unroll
      for (int nj = 0; nj < 4; ++nj)
        b4[nj] = *(const f32x4*)(b1 + cb * 256 + wcc * 64 + nj * 16 + (l4 << 2));
#pragma unroll
      for (int mi = 0; mi < 4; ++mi) {
        const int m = wrr * 64 + mi * 16 + l15;
#pragma unroll
        for (int nj = 0; nj < 4; ++nj) {
          u16x4 p;
#pragma unroll
          for (int reg = 0; reg < 4; ++reg)
            p[reg] = f2b(gelu_fast(acc[mi][nj][reg] + b4[nj][reg]));
          const int kt   = wcc * 2 + (nj >> 1);
          const int slot = ((nj & 1) << 1) + (l4 >> 1);
          *(u16x4*)(H + kt * 4096 + m * 32 +
                    ((slot ^ ((m >> 1) & 3)) << 3) + ((l4 & 1) << 2)) = p;
        }
      }
    }
    __syncthreads();   // H complete; all GEMM1 reads done

    // ---------------- GEMM2: acc2 += hidden_cb @ w2[:, cb*256..+256)^T ----
    {
      u16 *gc = bb0, *gn = bb1, *go = bb2;
      for (int kt = 0; kt < 8; ++kt) {
        if (kt + 1 < 8) {
          const int ko = (kt + 1) << 5;
          gload16(qB + ko, gn + 4096 + wbase);
          gload16(qB2 + ko, gn + 8192 + wbase);
          asm volatile("s_waitcnt vmcnt(2)" ::: "memory");
        } else {
          asm volatile("s_waitcnt vmcnt(0)" ::: "memory");
        }
        __builtin_amdgcn_s_barrier();
        asm volatile("" ::: "memory");
        {
          const u16* Hk = H + kt * 4096;
          bf16x8 af[4], bfv[4];
#pragma unroll
          for (int mi = 0; mi < 4; ++mi)
            af[mi] = *(const bf16x8*)(Hk + (wrr * 64 + mi * 16 + l15) * 32 +
                                      ((l4 ^ ksw2) << 3));
#pragma unroll
          for (int nj = 0; nj < 4; ++nj) bfv[nj] = RD_B(gc);
#pragma unroll
          for (int mi = 0; mi < 4; ++mi)
#pragma unroll
            for (int nj = 0; nj < 4; ++nj)
              acc2[mi][nj] = __builtin_amdgcn_mfma_f32_16x16x32_bf16(
                  bfv[nj], af[mi], acc2[mi][nj], 0, 0, 0);
        }
        asm volatile("" ::: "memory");
        u16* tmp = gc; gc = gn; gn = go; go = tmp;   // rotate (no 2nd barrier)
      }
    }
    __syncthreads();   // cb boundary: staging buffers + H free for reuse
  }
#undef RD_A
#undef RD_B

  // ---------------- epilogue: o = y + acc2 + b2; fused un-window ----------
  {
    f32x4 b4[4];
#pragma unroll
    for (int nj = 0; nj < 4; ++nj)
      b4[nj] = *(const f32x4*)(b2 + wcc * 64 + nj * 16 + (l4 << 2));
#pragma unroll
    for (int mi = 0; mi < 4; ++mi) {
      const int m = row0 + wrr * 64 + mi * 16 + l15;
      const float* yrow = y + (long)m * 256;
#pragma unroll
      for (int nj = 0; nj < 4; ++nj) {
        const int n = wcc * 64 + nj * 16 + (l4 << 2);
        const f32x4 yv = *(const f32x4*)(yrow + n);
#pragma unroll
        for (int reg = 0; reg < 4; ++reg)
          acc2[mi][nj][reg] += yv[reg] + b4[nj][reg];
      }
    }
    // 128 rows = 2 windows (same wh, ww = wwb, wwb+1) = 8 img rows x 16 cols
    const int wr0 = row0 >> 6;
    const int b = wr0 / 784, rem = wr0 % 784;
    const int wh = rem / 28, wwb = rem % 28;       // wwb even
    float* tp = (float*)smem;                      // [64 c][128 px] f32, swizzled
    const int pidx = tid & 127, cgrp = tid >> 7;   // 4 cgrps x 128 px
    const int pr = pidx >> 4, pc = pidx & 15;
    int hp = wh * 8 + 4 + pr;  if (hp >= 224) hp -= 224;
    int wp = wwb * 8 + 4 + pc; if (wp >= 224) wp -= 224;
    float* ob = oout + (long)b * 256 * 50176 + hp * 224 + wp;
#pragma unroll
    for (int cc = 0; cc < 4; ++cc) {
      __syncthreads();
      if (wcc == cc) {
#pragma unroll
        for (int mi = 0; mi < 4; ++mi) {
          const int ml = wrr * 64 + mi * 16 + l15;
          const int px = ((ml & 63) >> 3) * 16 + (ml >> 6) * 8 + (ml & 7);
#pragma unroll
          for (int nj = 0; nj < 4; ++nj)
#pragma unroll
            for (int reg = 0; reg < 4; ++reg)
              tp[(nj * 16 + (l4 << 2) + reg) * 128 + (px ^ (l4 << 2))] =
                  acc2[mi][nj][reg];
        }
      }
      __syncthreads();
#pragma unroll 4
      for (int j = 0; j < 16; ++j) {
        const int cl = cgrp * 16 + j;
        ob[(long)(cc * 64 + cl) * 50176] =
            tp[cl * 128 + (pidx ^ (((cl >> 2) & 3) << 2))];
      }
    }
  }
}

// ---------- per-window attention: 1 wave = 1 head ----------
__global__ __launch_bounds__(256)
void attn_win(const u16* __restrict__ qkv, const float* __restrict__ rpb,
              u16* __restrict__ aout) {
  __shared__ u16 Pl[4][4096];
  __shared__ float srpb[1800];
  const int tid = threadIdx.x, lane = tid & 63, wv = tid >> 6;
  const int bid = blockIdx.x;
  const int r = bid >> 1;
  const int h = (bid & 1) * 4 + wv;
  for (int i = tid; i < 1800; i += 256) srpb[i] = rpb[i];
  __syncthreads();

  // reference quirk: jnp.repeat(mask, B, axis=0) -> window r uses mask[r/4]
  const int midx = r >> 2;
  const int wh = midx / 28, ww = midx % 28;
  const int l15 = lane & 15, l4 = lane >> 4;

  u16* Pw = &Pl[wv][0];
  const long hb = (long)(r * 8 + h) * 2048;
  const u16* qh = qkv + hb;
  const u16* kh = qkv + 51380224 + hb;
  const u16* vh = qkv + 102760448 + hb;

  int rj[4], cj[4], labj[4];
#pragma unroll
  for (int nj = 0; nj < 4; ++nj) {
    const int j = nj * 16 + l15;
    rj[nj] = j >> 3; cj[nj] = j & 7;
    const int hp = wh * 8 + rj[nj], wp = ww * 8 + cj[nj];
    const int lh = (hp < 216) ? 0 : ((hp < 220) ? 1 : 2);
    const int lw = (wp < 216) ? 0 : ((wp < 220) ? 1 : 2);
    labj[nj] = lh * 3 + lw;
  }

  const f32x4 vzero = {0.f, 0.f, 0.f, 0.f};

  bf16x8 qf[4], kf[4];
#pragma unroll
  for (int mi = 0; mi < 4; ++mi)
    qf[mi] = *(const bf16x8*)(qh + (mi * 16 + l15) * 32 + l4 * 8);
#pragma unroll
  for (int nj = 0; nj < 4; ++nj)
    kf[nj] = *(const bf16x8*)(kh + (nj * 16 + l15) * 32 + l4 * 8);

  f32x4 S[4][4];
#pragma unroll
  for (int mi = 0; mi < 4; ++mi)
#pragma unroll
    for (int nj = 0; nj < 4; ++nj)
      S[mi][nj] = __builtin_amdgcn_mfma_f32_16x16x32_bf16(qf[mi], kf[nj], vzero, 0, 0, 0);

  // softmax (row-parallel over 16-lane groups) + normalized bf16 P -> LDS
#pragma unroll
  for (int mi = 0; mi < 4; ++mi)
#pragma unroll
    for (int reg = 0; reg < 4; ++reg) {
      const int i = mi * 16 + (l4 << 2) + reg;
      const int ri = i >> 3, ci = i & 7;
      const int hp = wh * 8 + ri, wp = ww * 8 + ci;
      const int lh = (hp < 216) ? 0 : ((hp < 220) ? 1 : 2);
      const int lw = (wp < 216) ? 0 : ((wp < 220) ? 1 : 2);
      const int li = lh * 3 + lw;
      float v[4];
#pragma unroll
      for (int nj = 0; nj < 4; ++nj) {
        const int idx = (ri - rj[nj] + 7) * 15 + (ci - cj[nj] + 7);
        v[nj] = S[mi][nj][reg] * 0.17677669529663687f + srpb[idx * 8 + h]
              + ((li != labj[nj]) ? -100.0f : 0.0f);
      }
      float mx = fmaxf(fmaxf(v[0], v[1]), fmaxf(v[2], v[3]));
      mx = fmaxf(mx, __shfl_xor(mx, 1));
      mx = fmaxf(mx, __shfl_xor(mx, 2));
      mx = fmaxf(mx, __shfl_xor(mx, 4));
      mx = fmaxf(mx, __shfl_xor(mx, 8));
      float sum = 0.f;
#pragma unroll
      for (int nj = 0; nj < 4; ++nj) { v[nj] = __expf(v[nj] - mx); sum += v[nj]; }
      sum += __shfl_xor(sum, 1);
      sum += __shfl_xor(sum, 2);
      sum += __shfl_xor(sum, 4);
      sum += __shfl_xor(sum, 8);
      const float rinv = __builtin_amdgcn_rcpf(sum);
      const int sw = (i & 7) << 3;
#pragma unroll
      for (int nj = 0; nj < 4; ++nj)
        Pw[i * 64 + ((nj * 16 + l15) ^ sw)] = f2b(v[nj] * rinv);
    }

  // PV: O^T = mfma(V^T, P) — per-wave LDS, no barrier needed
  f32x4 OT[2][4];
#pragma unroll
  for (int td = 0; td < 2; ++td)
#pragma unroll
    for (int ti = 0; ti < 4; ++ti) OT[td][ti] = vzero;

  const int rsw = (l15 & 7) << 3;
#pragma unroll
  for (int kk = 0; kk < 2; ++kk) {
    bf16x8 pf[4], vf[2];
#pragma unroll
    for (int ti = 0; ti < 4; ++ti)
      pf[ti] = *(const bf16x8*)(Pw + (ti * 16 + l15) * 64 + ((kk * 32 + l4 * 8) ^ rsw));
#pragma unroll
    for (int td = 0; td < 2; ++td)
      vf[td] = *(const bf16x8*)(vh + (td * 16 + l15) * 64 + kk * 32 + l4 * 8);
#pragma unroll
    for (int td = 0; td < 2; ++td)
#pragma unroll
      for (int ti = 0; ti < 4; ++ti)
        OT[td][ti] = __builtin_amdgcn_mfma_f32_16x16x32_bf16(vf[td], pf[ti], OT[td][ti], 0, 0, 0);
  }

  // write: lane holds O[i=ti*16+l15][d=td*16+4*l4+reg] -> u16x4 along d
#pragma unroll
  for (int td = 0; td < 2; ++td)
#pragma unroll
    for (int ti = 0; ti < 4; ++ti) {
      const int i = ti * 16 + l15;
      const int d0 = td * 16 + (l4 << 2);
      u16x4 p;
#pragma unroll
      for (int reg = 0; reg < 4; ++reg) p[reg] = f2b(OT[td][ti][reg]);
      *(u16x4*)(aout + (long)(r * 64 + i) * 256 + h * 32 + d0) = p;
    }
}

// ---------- launch ----------
extern "C" void kernel_launch(void* const* d_in, const int* in_sizes, int n_in,
                              void* d_out, int out_size, void* d_ws, size_t ws_size,
                              hipStream_t stream) {
  (void)in_sizes; (void)n_in; (void)out_size; (void)ws_size;
  const float* x     = (const float*)d_in[0];
  const float* qkvw  = (const float*)d_in[1];
  const float* projw = (const float*)d_in[2];
  const float* projb = (const float*)d_in[3];
  const float* rpb   = (const float*)d_in[4];
  const float* n1w   = (const float*)d_in[5];
  const float* n1b   = (const float*)d_in[6];
  const float* n2w   = (const float*)d_in[7];
  const float* n2b   = (const float*)d_in[8];
  const float* w1    = (const float*)d_in[9];
  const float* b1    = (const float*)d_in[10];
  const float* w2    = (const float*)d_in[11];
  const float* b2    = (const float*)d_in[12];

  char* ws = (char*)d_ws;
  u16*   hbuf   = (u16*)(ws);                  // 102,760,448 B : h, later h2
  u16*   qkvb   = (u16*)(ws + 102760448);      // 308,281,344 B : q|k|v
  u16*   abuf   = (u16*)(ws + 411041792);      // 102,760,448 B : attn out
  float* ybuf   = (float*)(ws + 513802240);    // 205,520,896 B : fp32 residual stream
  u16*   qkvwb  = (u16*)(ws + 719323136);
  u16*   projwb = (u16*)(ws + 719716352);
  u16*   w1b    = (u16*)(ws + 719847424);
  u16*   w2b    = (u16*)(ws + 720371712);      // end: 720,896,000 B

  conv_weights<<<3072, 256, 0, stream>>>(qkvw, projw, w1, w2, qkvwb, projwb, w1b, w2b);
  ln1_win<<<784, 256, 0, stream>>>(x, n1w, n1b, hbuf, ybuf);
  gemm_bt<0, 3><<<1568, 512, 0, stream>>>(hbuf, qkvwb, 256, nullptr, nullptr, qkvb, nullptr, nullptr);
  attn_win<<<6272, 256, 0, stream>>>(qkvb, rpb, abuf);
  gemm_bt<1, 1><<<1568, 512, 0, stream>>>(abuf, projwb, 256, ybuf, projb, hbuf, n2w, n2b);
  mlp_fused<<<1568, 512, 0, stream>>>(hbuf, w1b, w2b, ybuf, b1, b2, (float*)d_out);
}

// Round 23
// 1022.261 us; speedup vs baseline: 1.0398x; 1.0088x over previous
//
#include <hip/hip_runtime.h>

typedef unsigned short u16;
typedef unsigned int   u32;
typedef __attribute__((ext_vector_type(8))) __bf16 bf16x8;
typedef __attribute__((ext_vector_type(4))) float  f32x4;
typedef __attribute__((ext_vector_type(4))) u16    u16x4;

#define DEV __device__ __forceinline__

// ---------- helpers ----------
DEV u16 f2b(float f) {               // fp32 -> bf16 bits, RNE
  union { float f; u32 u; } a; a.f = f;
  const u32 u = a.u;
  return (u16)((u + 0x7fffu + ((u >> 16) & 1u)) >> 16);
}

// tanh-form GELU as x*sigmoid(1.5957691*(x+0.044715 x^3)); exp2-folded.
DEV float gelu_fast(float x) {
  const float x2 = x * x;
  const float t  = __builtin_fmaf(0.1029430f, x2, 2.3022150f);  // *log2(e) folded
  const float e  = __builtin_exp2f(x * t);
  const float r  = __builtin_amdgcn_rcpf(1.0f + e);
  return __builtin_fmaf(-x, r, x);   // x - x/(1+e) = x*sigmoid(z)
}

DEV void gload16(const void* g, void* l) {
  __builtin_amdgcn_global_load_lds(
      (const __attribute__((address_space(1))) void*)g,
      (__attribute__((address_space(3))) void*)l, 16, 0, 0);
}

// ---------- weight conversion (fp32 -> bf16) ----------
__global__ __launch_bounds__(256)
void conv_weights(const float* __restrict__ qkvw, const float* __restrict__ projw,
                  const float* __restrict__ w1,   const float* __restrict__ w2,
                  u16* __restrict__ dq, u16* __restrict__ dp,
                  u16* __restrict__ d1, u16* __restrict__ d2) {
  const int t = blockIdx.x * 256 + threadIdx.x;
  if (t < 196608)      dq[t]          = f2b(qkvw[t]);
  else if (t < 262144) dp[t - 196608] = f2b(projw[t - 196608]);
  else if (t < 524288) d1[t - 262144] = f2b(w1[t - 262144]);
  else                 d2[t - 524288] = f2b(w2[t - 524288]);
}

// ---------- window gather + LN1, 4 adjacent windows per block ----------
__global__ __launch_bounds__(256)
void ln1_win(const float* __restrict__ x, const float* __restrict__ w1,
             const float* __restrict__ b1, u16* __restrict__ hout,
             float* __restrict__ xwout) {
  __shared__ float xt[64 * 257];
  __shared__ float smean[256], srstd[256];
  const int tid = threadIdx.x, lane = tid & 63, wv = tid >> 6;
  const int g = blockIdx.x;
  const int b = g / 196, rem = g % 196;
  const int wh = rem / 7, wg = rem % 7;
  const int base_r = b * 784 + wh * 28 + wg * 4;
  const int pr = tid >> 5, pc = tid & 31;
  int hp = wh * 8 + 4 + pr; if (hp >= 224) hp -= 224;
  int wp = wg * 32 + 4 + pc; if (wp >= 224) wp -= 224;
  const long roff = (long)b * 256 * 50176 + hp * 224 + wp;

  float s = 0.f, q = 0.f;
  for (int cc = 0; cc < 4; ++cc) {
#pragma unroll 8
    for (int i = 0; i < 64; ++i) {
      const int c = cc * 64 + i;
      const float v = x[(long)c * 50176 + roff];
      xt[i * 257 + tid] = v;
      s += v; q += v * v;
    }
    __syncthreads();
#pragma unroll 8
    for (int jj = 0; jj < 64; ++jj) {
      const int p = jj * 4 + wv;
      const int m = (base_r + ((p & 31) >> 3)) * 64 + (p >> 5) * 8 + (p & 7);
      xwout[(long)m * 256 + cc * 64 + lane] = xt[lane * 257 + p];
    }
    __syncthreads();
  }
  const float mean = s * (1.f / 256.f);
  smean[tid] = mean;
  srstd[tid] = rsqrtf(q * (1.f / 256.f) - mean * mean + 1e-5f);
  __syncthreads();

  float wr_[4], br_[4];
#pragma unroll
  for (int cc = 0; cc < 4; ++cc) { wr_[cc] = w1[cc * 64 + lane]; br_[cc] = b1[cc * 64 + lane]; }
#pragma unroll 2
  for (int jj = 0; jj < 64; ++jj) {
    const int p = jj * 4 + wv;
    const int m = (base_r + ((p & 31) >> 3)) * 64 + (p >> 5) * 8 + (p & 7);
    const float mu = smean[p], rs = srstd[p];
#pragma unroll
    for (int cc = 0; cc < 4; ++cc) {
      const float v = xwout[(long)m * 256 + cc * 64 + lane];
      hout[(long)m * 256 + cc * 64 + lane] = f2b((v - mu) * rs * wr_[cc] + br_[cc]);
    }
  }
}

// ---------- 128xNx(BK=32) bf16 GEMM (r11-measured), B given as [N][K] ----------
// In-block N-loop, 48 KB LDS dbuf, counted vmcnt(3), BK32 XOR swizzle.
// EPI 0: qkv (NCOL=3): cb<2 -> q|k u16x4 along d; cb==2 -> v^T
// EPI 1: y += acc + bias (float4 RMW) + FUSED LN2 -> bout bf16 (NCOL=1)
template<int EPI, int NCOL>
__global__ __launch_bounds__(512, 4)
void gemm_bt(const u16* __restrict__ A, const u16* __restrict__ Bw, const int K,
             float* __restrict__ fout, const float* __restrict__ bias,
             u16* __restrict__ bout,
             const float* __restrict__ lnw, const float* __restrict__ lnb) {
  __shared__ __align__(16) u16 smem[24576];   // 48 KB
  u16* sA0 = smem;             // 128x32
  u16* sB0 = smem + 4096;      // 256x32
  u16* sA1 = smem + 12288;
  u16* sB1 = smem + 16384;

  const int tid  = threadIdx.x;
  const int lane = tid & 63;
  const int wid  = tid >> 6;
  const int wrr  = wid >> 2;
  const int wcc  = wid & 3;

  const int nwg = gridDim.x;
  const int bid = blockIdx.x;
  const int wg  = (bid & 7) * (nwg >> 3) + (bid >> 3);   // XCD chunk swizzle
  const int row0 = wg * 128;

  const f32x4 vzero = {0.f, 0.f, 0.f, 0.f};

  const int l15  = lane & 15;
  const int l4   = lane >> 4;
  const int ksw2 = (l15 >> 1) & 3;
  const int lcol = (((tid & 3) ^ ((tid >> 3) & 3)) << 3);

  const u16* pA = A + (long)(row0 + (tid >> 2)) * K + lcol;
  const int wbase = wid * 512;

#define STAGE_TILE(KT, DA, DB)                  \
  {                                             \
    gload16(pA  + (KT), (DA) + wbase);          \
    gload16(pB  + (KT), (DB) + wbase);          \
    gload16(pB2 + (KT), (DB) + 4096 + wbase);   \
  }

#define COMPUTE_TILE(SA, SB, SWAP)                                                      \
  {                                                                                     \
    bf16x8 af[4], bfv[4];                                                               \
    _Pragma("unroll")                                                                   \
    for (int mi = 0; mi < 4; ++mi)                                                      \
      af[mi] = *(const bf16x8*)((SA) + (wrr * 64 + mi * 16 + l15) * 32 +                \
                                ((l4 ^ ksw2) << 3));                                    \
    _Pragma("unroll")                                                                   \
    for (int nj = 0; nj < 4; ++nj)                                                      \
      bfv[nj] = *(const bf16x8*)((SB) + (wcc * 64 + nj * 16 + l15) * 32 +               \
                                 ((l4 ^ ksw2) << 3));                                   \
    _Pragma("unroll")                                                                   \
    for (int mi = 0; mi < 4; ++mi)                                                      \
      _Pragma("unroll")                                                                 \
      for (int nj = 0; nj < 4; ++nj) {                                                  \
        if (SWAP)                                                                       \
          acc[mi][nj] = __builtin_amdgcn_mfma_f32_16x16x32_bf16(bfv[nj], af[mi],        \
                                                                acc[mi][nj], 0, 0, 0);  \
        else                                                                            \
          acc[mi][nj] = __builtin_amdgcn_mfma_f32_16x16x32_bf16(af[mi], bfv[nj],        \
                                                                acc[mi][nj], 0, 0, 0);  \
      }                                                                                 \
  }

#define KLOOP(SWAP)                                                  \
  {                                                                  \
    const int nt = K >> 5;                                           \
    STAGE_TILE(0, sA0, sB0);                                         \
    int cur = 0;                                                     \
    for (int t = 0; t < nt; ++t) {                                   \
      u16* cA = cur ? sA1 : sA0;                                     \
      u16* cB = cur ? sB1 : sB0;                                     \
      u16* nA = cur ? sA0 : sA1;                                     \
      u16* nB = cur ? sB0 : sB1;                                     \
      if (t + 1 < nt) {                                              \
        STAGE_TILE((t + 1) << 5, nA, nB);                            \
        asm volatile("s_waitcnt vmcnt(3)" ::: "memory");             \
      } else {                                                       \
        asm volatile("s_waitcnt vmcnt(0)" ::: "memory");             \
      }                                                              \
      __builtin_amdgcn_s_barrier();                                  \
      asm volatile("" ::: "memory");                                 \
      COMPUTE_TILE(cA, cB, SWAP);                                    \
      asm volatile("" ::: "memory");                                 \
      __builtin_amdgcn_s_barrier();                                  \
      cur ^= 1;                                                      \
    }                                                                \
  }

#pragma unroll
  for (int cb = 0; cb < NCOL; ++cb) {
    const int col0 = cb * 256;
    const u16* pB  = Bw + (long)(col0 + (tid >> 2)) * K + lcol;
    const u16* pB2 = pB + (long)128 * K;

    f32x4 acc[4][4];
#pragma unroll
    for (int i = 0; i < 4; ++i)
#pragma unroll
      for (int j = 0; j < 4; ++j) acc[i][j] = vzero;

    if (EPI == 0 && cb == 2) {
      // ---- v: unswapped orientation, v^T scatter (lane=n(d), reg=m(ii)) ----
      KLOOP(0);
#pragma unroll
      for (int mi = 0; mi < 4; ++mi) {
        const int mb = row0 + wrr * 64 + mi * 16 + (l4 << 2);
        const int rrg = mb >> 6, ii = mb & 63;
#pragma unroll
        for (int nj = 0; nj < 4; ++nj) {
          const int n = 512 + wcc * 64 + nj * 16 + l15;
          const int hh = (n >> 5) & 7, d = n & 31;
          u16x4 p;
#pragma unroll
          for (int reg = 0; reg < 4; ++reg) p[reg] = f2b(acc[mi][nj][reg]);
          *(u16x4*)(bout + 102760448L + (long)((rrg * 8 + hh) * 32 + d) * 64 + ii) = p;
        }
      }
      continue;
    }

    KLOOP(1);

    if (EPI == 0) {
      // q|k scatter, swapped orientation: lane=m, reg=n(d)
#pragma unroll
      for (int mi = 0; mi < 4; ++mi) {
        const int m = row0 + wrr * 64 + mi * 16 + l15;
        const int rr = m >> 6, ii = m & 63;
#pragma unroll
        for (int nj = 0; nj < 4; ++nj) {
          const int n = col0 + wcc * 64 + nj * 16 + (l4 << 2);
          const int s = n >> 8, hh = (n >> 5) & 7, d = n & 31;
          u16x4 p;
#pragma unroll
          for (int reg = 0; reg < 4; ++reg) p[reg] = f2b(acc[mi][nj][reg]);
          *(u16x4*)(bout + (long)s * 51380224L +
                    (long)((rr * 8 + hh) * 64 + ii) * 32 + d) = p;
        }
      }
    } else if (EPI == 1) {
      // y += acc + bias (float4 RMW), then fused LN2 -> bout (bf16 [m][256])
      f32x4 b4[4];
#pragma unroll
      for (int nj = 0; nj < 4; ++nj)
        b4[nj] = *(const f32x4*)(bias + wcc * 64 + nj * 16 + (l4 << 2));
      float sS[4], sQ[4];
#pragma unroll
      for (int mi = 0; mi < 4; ++mi) {
        const int m = row0 + wrr * 64 + mi * 16 + l15;
        float* yrow = fout + (long)m * 256;
        float s = 0.f, q = 0.f;
#pragma unroll
        for (int nj = 0; nj < 4; ++nj) {
          const int n = wcc * 64 + nj * 16 + (l4 << 2);
          f32x4 o = *(f32x4*)(yrow + n);
#pragma unroll
          for (int reg = 0; reg < 4; ++reg) {
            o[reg] += acc[mi][nj][reg] + b4[nj][reg];
            s += o[reg]; q += o[reg] * o[reg];
          }
          *(f32x4*)(yrow + n) = o;
          acc[mi][nj] = o;
        }
        s += __shfl_xor(s, 16); s += __shfl_xor(s, 32);
        q += __shfl_xor(q, 16); q += __shfl_xor(q, 32);
        sS[mi] = s; sQ[mi] = q;
      }
      float* ps = (float*)smem;          // [128 rows][4 wcc]
      float* pq = ps + 512;
      __syncthreads();
      if (lane < 16) {
#pragma unroll
        for (int mi = 0; mi < 4; ++mi) {
          const int idx = (wrr * 64 + mi * 16 + l15) * 4 + wcc;
          ps[idx] = sS[mi]; pq[idx] = sQ[mi];
        }
      }
      __syncthreads();
#pragma unroll
      for (int mi = 0; mi < 4; ++mi) {
        const int m = row0 + wrr * 64 + mi * 16 + l15;
        const int base = (wrr * 64 + mi * 16 + l15) * 4;
        const float S = ps[base] + ps[base + 1] + ps[base + 2] + ps[base + 3];
        const float Q = pq[base] + pq[base + 1] + pq[base + 2] + pq[base + 3];
        const float mean = S * (1.f / 256.f);
        const float rstd = rsqrtf(Q * (1.f / 256.f) - mean * mean + 1e-5f);
#pragma unroll
        for (int nj = 0; nj < 4; ++nj) {
          const int n = wcc * 64 + nj * 16 + (l4 << 2);
          const f32x4 w4 = *(const f32x4*)(lnw + n);
          const f32x4 c4 = *(const f32x4*)(lnb + n);
          u16x4 p;
#pragma unroll
          for (int reg = 0; reg < 4; ++reg)
            p[reg] = f2b((acc[mi][nj][reg] - mean) * rstd * w4[reg] + c4[reg]);
          *(u16x4*)(bout + (long)m * 256 + n) = p;
        }
      }
    }
  }
#undef STAGE_TILE
#undef COMPUTE_TILE
#undef KLOOP
}

// ---------- FUSED MLP v7: r22 + 2-in-flight prefetch (3 bufs, 2 barriers) ----------
// In the 1-block/CU no-TLP regime the exposed load latency (~2000cy/K-step)
// is the binding term; 2-deep staging doubles the cover window (~800cy >
// HBM-cold ~900cy approx). Race: stage(t+2) targets the buffer computed at
// t-2 -> trailing barrier REQUIRED (all waves past compute(t-2) via barrier
// of step t-1). GEMM1 vmcnt(6)/(3)/(0); GEMM2 vmcnt(4)/(2)/(0), both first
// stages pre-issued before the GELU (latency hides under ~500cy VALU).
// 1 block/CU deliberate: all occupancy variants regressed via memory system
// (r15/r19: L2 thrash; r21: write fragmentation). FETCH 179 MB, WRITE 218 MB.
__global__ __launch_bounds__(512, 2)
void mlp_fused(const u16* __restrict__ A, const u16* __restrict__ w1b,
               const u16* __restrict__ w2b, const float* __restrict__ y,
               const float* __restrict__ b1, const float* __restrict__ b2,
               float* __restrict__ oout) {
  __shared__ __align__(16) u16 smem[69632];   // 136 KB
  u16* bb0 = smem;                 // A @ +0 (8 KB), B @ +4096 (16 KB)
  u16* bb1 = smem + 12288;
  u16* bb2 = smem + 24576;
  u16* H   = smem + 36864;         // 8 kt x 128 x 32 (64 KB)

  const int tid  = threadIdx.x;
  const int lane = tid & 63;
  const int wid  = tid >> 6;
  const int wrr  = wid >> 2;
  const int wcc  = wid & 3;

  const int nwg = gridDim.x;
  const int bid = blockIdx.x;
  const int wg  = (bid & 7) * (nwg >> 3) + (bid >> 3);
  const int row0 = wg * 128;

  const f32x4 vzero = {0.f, 0.f, 0.f, 0.f};
  const int l15  = lane & 15;
  const int l4   = lane >> 4;
  const int ksw2 = (l15 >> 1) & 3;
  const int lcol = (((tid & 3) ^ ((tid >> 3) & 3)) << 3);

  const u16* pA = A + (long)(row0 + (tid >> 2)) * 256 + lcol;
  const int wbase = wid * 512;

  f32x4 acc2[4][4];
#pragma unroll
  for (int i = 0; i < 4; ++i)
#pragma unroll
    for (int j = 0; j < 4; ++j) acc2[i][j] = vzero;

#define RD_A(BUF) \
  (*(const bf16x8*)((BUF) + (wrr * 64 + mi * 16 + l15) * 32 + ((l4 ^ ksw2) << 3)))
#define RD_B(BUF) \
  (*(const bf16x8*)((BUF) + 4096 + (wcc * 64 + nj * 16 + l15) * 32 + ((l4 ^ ksw2) << 3)))

  for (int cb = 0; cb < 4; ++cb) {
    // ---------------- GEMM1: hidden_cb = h2 @ w1[cb*256..+256)^T ----------
    const u16* pB  = w1b + (long)(cb * 256 + (tid >> 2)) * 256 + lcol;
    const u16* pB2 = pB + 128 * 256;

    f32x4 acc[4][4];
#pragma unroll
    for (int i = 0; i < 4; ++i)
#pragma unroll
      for (int j = 0; j < 4; ++j) acc[i][j] = vzero;

    {
      u16 *bc = bb0, *bn = bb1, *bo = bb2;
      // prologue: stage tiles 0,1 (2-in-flight)
      gload16(pA, bc + wbase);
      gload16(pB, bc + 4096 + wbase);
      gload16(pB2, bc + 8192 + wbase);
      gload16(pA + 32, bn + wbase);
      gload16(pB + 32, bn + 4096 + wbase);
      gload16(pB2 + 32, bn + 8192 + wbase);
      for (int t = 0; t < 8; ++t) {
        if (t + 2 < 8) {
          const int kt = (t + 2) << 5;
          gload16(pA + kt, bo + wbase);
          gload16(pB + kt, bo + 4096 + wbase);
          gload16(pB2 + kt, bo + 8192 + wbase);
          asm volatile("s_waitcnt vmcnt(6)" ::: "memory");
        } else if (t + 1 < 8) {
          asm volatile("s_waitcnt vmcnt(3)" ::: "memory");
        } else {
          asm volatile("s_waitcnt vmcnt(0)" ::: "memory");
        }
        __builtin_amdgcn_s_barrier();
        asm volatile("" ::: "memory");
        {
          bf16x8 af[4], bfv[4];
#pragma unroll
          for (int mi = 0; mi < 4; ++mi) af[mi] = RD_A(bc);
#pragma unroll
          for (int nj = 0; nj < 4; ++nj) bfv[nj] = RD_B(bc);
#pragma unroll
          for (int mi = 0; mi < 4; ++mi)
#pragma unroll
            for (int nj = 0; nj < 4; ++nj)
              acc[mi][nj] = __builtin_amdgcn_mfma_f32_16x16x32_bf16(
                  bfv[nj], af[mi], acc[mi][nj], 0, 0, 0);
        }
        asm volatile("" ::: "memory");
        __builtin_amdgcn_s_barrier();          // trailing barrier (2-deep safety)
        u16* tmp = bc; bc = bn; bn = bo; bo = tmp;
      }
    }

    // pre-issue GEMM2's first TWO B-stages (latency hides under the gelu;
    // bb0/bb1 safe: last read at GEMM1 compute(6)/(7), trailing barrier passed)
    const u16* qB  = w2b + (long)(tid >> 2) * 1024 + cb * 256 + lcol;
    const u16* qB2 = qB + 128 * 1024;
    gload16(qB, bb0 + 4096 + wbase);
    gload16(qB2, bb0 + 8192 + wbase);
    gload16(qB + 32, bb1 + 4096 + wbase);
    gload16(qB2 + 32, bb1 + 8192 + wbase);

    // gelu + bf16 -> H (swizzled GEMM2-A layout). lane=m, reg quad = 4 k.
    {
      f32x4 b4[4];
#pragma unroll
      for (int nj = 0; nj < 4; ++nj)
        b4[nj] = *(const f32x4*)(b1 + cb * 256 + wcc * 64 + nj * 16 + (l4 << 2));
#pragma unroll
      for (int mi = 0; mi < 4; ++mi) {
        const int m = wrr * 64 + mi * 16 + l15;
#pragma unroll
        for (int nj = 0; nj < 4; ++nj) {
          u16x4 p;
#pragma unroll
          for (int reg = 0; reg < 4; ++reg)
            p[reg] = f2b(gelu_fast(acc[mi][nj][reg] + b4[nj][reg]));
          const int kt   = wcc * 2 + (nj >> 1);
          const int slot = ((nj & 1) << 1) + (l4 >> 1);
          *(u16x4*)(H + kt * 4096 + m * 32 +
                    ((slot ^ ((m >> 1) & 3)) << 3) + ((l4 & 1) << 2)) = p;
        }
      }
    }
    __syncthreads();   // H complete; all GEMM1 reads done

    // ---------------- GEMM2: acc2 += hidden_cb @ w2[:, cb*256..+256)^T ----
    {
      u16 *gc = bb0, *gn = bb1, *go = bb2;
      for (int kt = 0; kt < 8; ++kt) {
        if (kt + 2 < 8) {
          const int ko = (kt + 2) << 5;
          gload16(qB + ko, go + 4096 + wbase);
          gload16(qB2 + ko, go + 8192 + wbase);
          asm volatile("s_waitcnt vmcnt(4)" ::: "memory");
        } else if (kt + 1 < 8) {
          asm volatile("s_waitcnt vmcnt(2)" ::: "memory");
        } else {
          asm volatile("s_waitcnt vmcnt(0)" ::: "memory");
        }
        __builtin_amdgcn_s_barrier();
        asm volatile("" ::: "memory");
        {
          const u16* Hk = H + kt * 4096;
          bf16x8 af[4], bfv[4];
#pragma unroll
          for (int mi = 0; mi < 4; ++mi)
            af[mi] = *(const bf16x8*)(Hk + (wrr * 64 + mi * 16 + l15) * 32 +
                                      ((l4 ^ ksw2) << 3));
#pragma unroll
          for (int nj = 0; nj < 4; ++nj) bfv[nj] = RD_B(gc);
#pragma unroll
          for (int mi = 0; mi < 4; ++mi)
#pragma unroll
            for (int nj = 0; nj < 4; ++nj)
              acc2[mi][nj] = __builtin_amdgcn_mfma_f32_16x16x32_bf16(
                  bfv[nj], af[mi], acc2[mi][nj], 0, 0, 0);
        }
        asm volatile("" ::: "memory");
        __builtin_amdgcn_s_barrier();          // trailing barrier (2-deep safety)
        u16* tmp = gc; gc = gn; gn = go; go = tmp;
      }
    }
    __syncthreads();   // cb boundary: staging buffers + H free for reuse
  }
#undef RD_A
#undef RD_B

  // ---------------- epilogue: o = y + acc2 + b2; fused un-window ----------
  {
    f32x4 b4[4];
#pragma unroll
    for (int nj = 0; nj < 4; ++nj)
      b4[nj] = *(const f32x4*)(b2 + wcc * 64 + nj * 16 + (l4 << 2));
#pragma unroll
    for (int mi = 0; mi < 4; ++mi) {
      const int m = row0 + wrr * 64 + mi * 16 + l15;
      const float* yrow = y + (long)m * 256;
#pragma unroll
      for (int nj = 0; nj < 4; ++nj) {
        const int n = wcc * 64 + nj * 16 + (l4 << 2);
        const f32x4 yv = *(const f32x4*)(yrow + n);
#pragma unroll
        for (int reg = 0; reg < 4; ++reg)
          acc2[mi][nj][reg] += yv[reg] + b4[nj][reg];
      }
    }
    // 128 rows = 2 windows (same wh, ww = wwb, wwb+1) = 8 img rows x 16 cols
    const int wr0 = row0 >> 6;
    const int b = wr0 / 784, rem = wr0 % 784;
    const int wh = rem / 28, wwb = rem % 28;       // wwb even
    float* tp = (float*)smem;                      // [64 c][128 px] f32, swizzled
    const int pidx = tid & 127, cgrp = tid >> 7;   // 4 cgrps x 128 px
    const int pr = pidx >> 4, pc = pidx & 15;
    int hp = wh * 8 + 4 + pr;  if (hp >= 224) hp -= 224;
    int wp = wwb * 8 + 4 + pc; if (wp >= 224) wp -= 224;
    float* ob = oout + (long)b * 256 * 50176 + hp * 224 + wp;
#pragma unroll
    for (int cc = 0; cc < 4; ++cc) {
      __syncthreads();
      if (wcc == cc) {
#pragma unroll
        for (int mi = 0; mi < 4; ++mi) {
          const int ml = wrr * 64 + mi * 16 + l15;
          const int px = ((ml & 63) >> 3) * 16 + (ml >> 6) * 8 + (ml & 7);
#pragma unroll
          for (int nj = 0; nj < 4; ++nj)
#pragma unroll
            for (int reg = 0; reg < 4; ++reg)
              tp[(nj * 16 + (l4 << 2) + reg) * 128 + (px ^ (l4 << 2))] =
                  acc2[mi][nj][reg];
        }
      }
      __syncthreads();
#pragma unroll 4
      for (int j = 0; j < 16; ++j) {
        const int cl = cgrp * 16 + j;
        ob[(long)(cc * 64 + cl) * 50176] =
            tp[cl * 128 + (pidx ^ (((cl >> 2) & 3) << 2))];
      }
    }
  }
}

// ---------- per-window attention: 1 wave = 1 head ----------
__global__ __launch_bounds__(256)
void attn_win(const u16* __restrict__ qkv, const float* __restrict__ rpb,
              u16* __restrict__ aout) {
  __shared__ u16 Pl[4][4096];
  __shared__ float srpb[1800];
  const int tid = threadIdx.x, lane = tid & 63, wv = tid >> 6;
  const int bid = blockIdx.x;
  const int r = bid >> 1;
  const int h = (bid & 1) * 4 + wv;
  for (int i = tid; i < 1800; i += 256) srpb[i] = rpb[i];
  __syncthreads();

  // reference quirk: jnp.repeat(mask, B, axis=0) -> window r uses mask[r/4]
  const int midx = r >> 2;
  const int wh = midx / 28, ww = midx % 28;
  const int l15 = lane & 15, l4 = lane >> 4;

  u16* Pw = &Pl[wv][0];
  const long hb = (long)(r * 8 + h) * 2048;
  const u16* qh = qkv + hb;
  const u16* kh = qkv + 51380224 + hb;
  const u16* vh = qkv + 102760448 + hb;

  int rj[4], cj[4], labj[4];
#pragma unroll
  for (int nj = 0; nj < 4; ++nj) {
    const int j = nj * 16 + l15;
    rj[nj] = j >> 3; cj[nj] = j & 7;
    const int hp = wh * 8 + rj[nj], wp = ww * 8 + cj[nj];
    const int lh = (hp < 216) ? 0 : ((hp < 220) ? 1 : 2);
    const int lw = (wp < 216) ? 0 : ((wp < 220) ? 1 : 2);
    labj[nj] = lh * 3 + lw;
  }

  const f32x4 vzero = {0.f, 0.f, 0.f, 0.f};

  bf16x8 qf[4], kf[4];
#pragma unroll
  for (int mi = 0; mi < 4; ++mi)
    qf[mi] = *(const bf16x8*)(qh + (mi * 16 + l15) * 32 + l4 * 8);
#pragma unroll
  for (int nj = 0; nj < 4; ++nj)
    kf[nj] = *(const bf16x8*)(kh + (nj * 16 + l15) * 32 + l4 * 8);

  f32x4 S[4][4];
#pragma unroll
  for (int mi = 0; mi < 4; ++mi)
#pragma unroll
    for (int nj = 0; nj < 4; ++nj)
      S[mi][nj] = __builtin_amdgcn_mfma_f32_16x16x32_bf16(qf[mi], kf[nj], vzero, 0, 0, 0);

  // softmax (row-parallel over 16-lane groups) + normalized bf16 P -> LDS
#pragma unroll
  for (int mi = 0; mi < 4; ++mi)
#pragma unroll
    for (int reg = 0; reg < 4; ++reg) {
      const int i = mi * 16 + (l4 << 2) + reg;
      const int ri = i >> 3, ci = i & 7;
      const int hp = wh * 8 + ri, wp = ww * 8 + ci;
      const int lh = (hp < 216) ? 0 : ((hp < 220) ? 1 : 2);
      const int lw = (wp < 216) ? 0 : ((wp < 220) ? 1 : 2);
      const int li = lh * 3 + lw;
      float v[4];
#pragma unroll
      for (int nj = 0; nj < 4; ++nj) {
        const int idx = (ri - rj[nj] + 7) * 15 + (ci - cj[nj] + 7);
        v[nj] = S[mi][nj][reg] * 0.17677669529663687f + srpb[idx * 8 + h]
              + ((li != labj[nj]) ? -100.0f : 0.0f);
      }
      float mx = fmaxf(fmaxf(v[0], v[1]), fmaxf(v[2], v[3]));
      mx = fmaxf(mx, __shfl_xor(mx, 1));
      mx = fmaxf(mx, __shfl_xor(mx, 2));
      mx = fmaxf(mx, __shfl_xor(mx, 4));
      mx = fmaxf(mx, __shfl_xor(mx, 8));
      float sum = 0.f;
#pragma unroll
      for (int nj = 0; nj < 4; ++nj) { v[nj] = __expf(v[nj] - mx); sum += v[nj]; }
      sum += __shfl_xor(sum, 1);
      sum += __shfl_xor(sum, 2);
      sum += __shfl_xor(sum, 4);
      sum += __shfl_xor(sum, 8);
      const float rinv = __builtin_amdgcn_rcpf(sum);
      const int sw = (i & 7) << 3;
#pragma unroll
      for (int nj = 0; nj < 4; ++nj)
        Pw[i * 64 + ((nj * 16 + l15) ^ sw)] = f2b(v[nj] * rinv);
    }

  // PV: O^T = mfma(V^T, P) — per-wave LDS, no barrier needed
  f32x4 OT[2][4];
#pragma unroll
  for (int td = 0; td < 2; ++td)
#pragma unroll
    for (int ti = 0; ti < 4; ++ti) OT[td][ti] = vzero;

  const int rsw = (l15 & 7) << 3;
#pragma unroll
  for (int kk = 0; kk < 2; ++kk) {
    bf16x8 pf[4], vf[2];
#pragma unroll
    for (int ti = 0; ti < 4; ++ti)
      pf[ti] = *(const bf16x8*)(Pw + (ti * 16 + l15) * 64 + ((kk * 32 + l4 * 8) ^ rsw));
#pragma unroll
    for (int td = 0; td < 2; ++td)
      vf[td] = *(const bf16x8*)(vh + (td * 16 + l15) * 64 + kk * 32 + l4 * 8);
#pragma unroll
    for (int td = 0; td < 2; ++td)
#pragma unroll
      for (int ti = 0; ti < 4; ++ti)
        OT[td][ti] = __builtin_amdgcn_mfma_f32_16x16x32_bf16(vf[td], pf[ti], OT[td][ti], 0, 0, 0);
  }

  // write: lane holds O[i=ti*16+l15][d=td*16+4*l4+reg] -> u16x4 along d
#pragma unroll
  for (int td = 0; td < 2; ++td)
#pragma unroll
    for (int ti = 0; ti < 4; ++ti) {
      const int i = ti * 16 + l15;
      const int d0 = td * 16 + (l4 << 2);
      u16x4 p;
#pragma unroll
      for (int reg = 0; reg < 4; ++reg) p[reg] = f2b(OT[td][ti][reg]);
      *(u16x4*)(aout + (long)(r * 64 + i) * 256 + h * 32 + d0) = p;
    }
}

// ---------- launch ----------
extern "C" void kernel_launch(void* const* d_in, const int* in_sizes, int n_in,
                              void* d_out, int out_size, void* d_ws, size_t ws_size,
                              hipStream_t stream) {
  (void)in_sizes; (void)n_in; (void)out_size; (void)ws_size;
  const float* x     = (const float*)d_in[0];
  const float* qkvw  = (const float*)d_in[1];
  const float* projw = (const float*)d_in[2];
  const float* projb = (const float*)d_in[3];
  const float* rpb   = (const float*)d_in[4];
  const float* n1w   = (const float*)d_in[5];
  const float* n1b   = (const float*)d_in[6];
  const float* n2w   = (const float*)d_in[7];
  const float* n2b   = (const float*)d_in[8];
  const float* w1    = (const float*)d_in[9];
  const float* b1    = (const float*)d_in[10];
  const float* w2    = (const float*)d_in[11];
  const float* b2    = (const float*)d_in[12];

  char* ws = (char*)d_ws;
  u16*   hbuf   = (u16*)(ws);                  // 102,760,448 B : h, later h2
  u16*   qkvb   = (u16*)(ws + 102760448);      // 308,281,344 B : q|k|v
  u16*   abuf   = (u16*)(ws + 411041792);      // 102,760,448 B : attn out
  float* ybuf   = (float*)(ws + 513802240);    // 205,520,896 B : fp32 residual stream
  u16*   qkvwb  = (u16*)(ws + 719323136);
  u16*   projwb = (u16*)(ws + 719716352);
  u16*   w1b    = (u16*)(ws + 719847424);
  u16*   w2b    = (u16*)(ws + 720371712);      // end: 720,896,000 B

  conv_weights<<<3072, 256, 0, stream>>>(qkvw, projw, w1, w2, qkvwb, projwb, w1b, w2b);
  ln1_win<<<784, 256, 0, stream>>>(x, n1w, n1b, hbuf, ybuf);
  gemm_bt<0, 3><<<1568, 512, 0, stream>>>(hbuf, qkvwb, 256, nullptr, nullptr, qkvb, nullptr, nullptr);
  attn_win<<<6272, 256, 0, stream>>>(qkvb, rpb, abuf);
  gemm_bt<1, 1><<<1568, 512, 0, stream>>>(abuf, projwb, 256, ybuf, projb, hbuf, n2w, n2b);
  mlp_fused<<<1568, 512, 0, stream>>>(hbuf, w1b, w2b, ybuf, b1, b2, (float*)d_out);
}